// Round 1
// baseline (1771.419 us; speedup 1.0000x reference)
//
#include <hip/hip_runtime.h>
#include <hip/hip_bf16.h>
#include <math.h>

#define SLEN 256
#define BSZ  16
#define NH   8
#define HD   64
#define HID  512
#define FFD  2048
#define MROWS (SLEN*BSZ)   // 4096

typedef __attribute__((ext_vector_type(8))) short short8v;
typedef __attribute__((ext_vector_type(4))) float float4v;
typedef unsigned short ushort_t;

// ---- all-VALU wave-64 reductions: 4 DPP xor levels + row_bcast15/31 + readlane ----
template<int C> __device__ __forceinline__ float dppf(float x){
  return __int_as_float(__builtin_amdgcn_update_dpp(__float_as_int(x), __float_as_int(x), C, 0xF, 0xF, false));
}

__device__ __forceinline__ float rsum64(float v){
  v += dppf<0xB1>(v);   // xor 1
  v += dppf<0x4E>(v);   // xor 2
  v += dppf<0x141>(v);  // row_half_mirror (xor 4 level)
  v += dppf<0x140>(v);  // row_mirror      (xor 8 level)
  v += __int_as_float(__builtin_amdgcn_update_dpp(0, __float_as_int(v), 0x142, 0xa, 0xF, false)); // bcast15
  v += __int_as_float(__builtin_amdgcn_update_dpp(0, __float_as_int(v), 0x143, 0xc, 0xF, false)); // bcast31
  return __int_as_float(__builtin_amdgcn_readlane(__float_as_int(v), 63));
}

__device__ __forceinline__ float rmax64(float v){
  v = fmaxf(v, dppf<0xB1>(v));
  v = fmaxf(v, dppf<0x4E>(v));
  v = fmaxf(v, dppf<0x141>(v));
  v = fmaxf(v, dppf<0x140>(v));
  v = fmaxf(v, __int_as_float(__builtin_amdgcn_update_dpp((int)0xff800000u, __float_as_int(v), 0x142, 0xa, 0xF, false)));
  v = fmaxf(v, __int_as_float(__builtin_amdgcn_update_dpp((int)0xff800000u, __float_as_int(v), 0x143, 0xc, 0xF, false)));
  return __int_as_float(__builtin_amdgcn_readlane(__float_as_int(v), 63));
}

__device__ __forceinline__ void split_bf16(float f, ushort_t& h, ushort_t& l){
  unsigned u = __float_as_uint(f);
  unsigned r = u + (0x7fffu + ((u >> 16) & 1u));
  h = (ushort_t)(r >> 16);
  float hf = __uint_as_float(((unsigned)h) << 16);
  float lo = f - hf;
  unsigned u2 = __float_as_uint(lo);
  unsigned r2 = u2 + (0x7fffu + ((u2 >> 16) & 1u));
  l = (ushort_t)(r2 >> 16);
}

// ---------------- MFMA GEMM, bf16x3 split (~fp32 accuracy) ----------------
template<int N, int K, bool BIAS, bool RESID, bool RELU>
__global__ __launch_bounds__(512) void gemm_mfma(
    const float* __restrict__ A, const float* __restrict__ B,
    const float* __restrict__ bias, const float* __restrict__ resid,
    float* __restrict__ C)
{
  __shared__ ushort_t Ah[128][40];
  __shared__ ushort_t Al[128][40];
  __shared__ ushort_t Bh[128][40];   // [col][k] (transposed)
  __shared__ ushort_t Bl[128][40];

  const int tid = threadIdx.x;
  const int wv = tid >> 6, lane = tid & 63;
  const int wm = wv >> 2, wn = wv & 3;
  const int l15 = lane & 15, l16 = lane >> 4;
  const int row0 = blockIdx.y * 128, col0 = blockIdx.x * 128;

  const int sar = tid >> 2, sak = (tid & 3) * 8;
  const int sbc = tid & 127, sbk = (tid >> 7) * 8;

  float4v acc[4][2];
#pragma unroll
  for (int i = 0; i < 4; ++i)
#pragma unroll
    for (int n = 0; n < 2; ++n) acc[i][n] = (float4v)(0.f);

  for (int k0 = 0; k0 < K; k0 += 32) {
    {
      const float* ap = &A[(size_t)(row0 + sar) * K + k0 + sak];
      float4 a0 = *reinterpret_cast<const float4*>(ap);
      float4 a1 = *reinterpret_cast<const float4*>(ap + 4);
      float av[8] = {a0.x, a0.y, a0.z, a0.w, a1.x, a1.y, a1.z, a1.w};
      short8v vh, vl;
#pragma unroll
      for (int j = 0; j < 8; ++j) {
        ushort_t h, l; split_bf16(av[j], h, l);
        vh[j] = (short)h; vl[j] = (short)l;
      }
      *reinterpret_cast<short8v*>(&Ah[sar][sak]) = vh;
      *reinterpret_cast<short8v*>(&Al[sar][sak]) = vl;
    }
    {
      float bv[8];
#pragma unroll
      for (int j = 0; j < 8; ++j)
        bv[j] = B[(size_t)(k0 + sbk + j) * N + col0 + sbc];
      short8v vh, vl;
#pragma unroll
      for (int j = 0; j < 8; ++j) {
        ushort_t h, l; split_bf16(bv[j], h, l);
        vh[j] = (short)h; vl[j] = (short)l;
      }
      *reinterpret_cast<short8v*>(&Bh[sbc][sbk]) = vh;
      *reinterpret_cast<short8v*>(&Bl[sbc][sbk]) = vl;
    }
    __syncthreads();

    short8v ah[4], al[4], bh[2], bl[2];
#pragma unroll
    for (int i = 0; i < 4; ++i) {
      const int r = wm * 64 + i * 16 + l15;
      ah[i] = *reinterpret_cast<const short8v*>(&Ah[r][l16 * 8]);
      al[i] = *reinterpret_cast<const short8v*>(&Al[r][l16 * 8]);
    }
#pragma unroll
    for (int n = 0; n < 2; ++n) {
      const int c = wn * 32 + n * 16 + l15;
      bh[n] = *reinterpret_cast<const short8v*>(&Bh[c][l16 * 8]);
      bl[n] = *reinterpret_cast<const short8v*>(&Bl[c][l16 * 8]);
    }
#pragma unroll
    for (int i = 0; i < 4; ++i)
#pragma unroll
      for (int n = 0; n < 2; ++n) {
        acc[i][n] = __builtin_amdgcn_mfma_f32_16x16x32_bf16(ah[i], bh[n], acc[i][n], 0, 0, 0);
        acc[i][n] = __builtin_amdgcn_mfma_f32_16x16x32_bf16(ah[i], bl[n], acc[i][n], 0, 0, 0);
        acc[i][n] = __builtin_amdgcn_mfma_f32_16x16x32_bf16(al[i], bh[n], acc[i][n], 0, 0, 0);
      }
    __syncthreads();
  }

#pragma unroll
  for (int i = 0; i < 4; ++i) {
#pragma unroll
    for (int n = 0; n < 2; ++n) {
      const int col = col0 + wn * 32 + n * 16 + l15;
      float bs = BIAS ? bias[col] : 0.f;
#pragma unroll
      for (int r = 0; r < 4; ++r) {
        const int row = row0 + wm * 64 + i * 16 + l16 * 4 + r;
        float v = acc[i][n][r] + bs;
        if (RESID) v += resid[(size_t)row * N + col];
        if (RELU)  v = fmaxf(v, 0.f);
        C[(size_t)row * N + col] = v;
      }
    }
  }
}

// ---------------- layernorm over HID=512 ----------------
__global__ __launch_bounds__(64) void layernorm_k(
    const float* __restrict__ in, const float* __restrict__ g,
    const float* __restrict__ b, float* __restrict__ out)
{
  const int row = blockIdx.x, lane = threadIdx.x;
  const float* p = in + (size_t)row * HID + lane * 8;
  float4 v0 = *reinterpret_cast<const float4*>(p);
  float4 v1 = *reinterpret_cast<const float4*>(p + 4);
  float s = v0.x + v0.y + v0.z + v0.w + v1.x + v1.y + v1.z + v1.w;
  s = rsum64(s);
  const float mean = s * (1.0f / HID);
  float x[8] = {v0.x, v0.y, v0.z, v0.w, v1.x, v1.y, v1.z, v1.w};
  float sq = 0.f;
#pragma unroll
  for (int j = 0; j < 8; ++j) { float d = x[j] - mean; sq += d * d; }
  sq = rsum64(sq);
  const float rstd = rsqrtf(sq * (1.0f / HID) + 1e-5f);
  float4 g0 = *reinterpret_cast<const float4*>(&g[lane * 8]);
  float4 g1 = *reinterpret_cast<const float4*>(&g[lane * 8 + 4]);
  float4 b0 = *reinterpret_cast<const float4*>(&b[lane * 8]);
  float4 b1 = *reinterpret_cast<const float4*>(&b[lane * 8 + 4]);
  float gg[8] = {g0.x, g0.y, g0.z, g0.w, g1.x, g1.y, g1.z, g1.w};
  float bb[8] = {b0.x, b0.y, b0.z, b0.w, b1.x, b1.y, b1.z, b1.w};
  float o[8];
#pragma unroll
  for (int j = 0; j < 8; ++j) o[j] = (x[j] - mean) * rstd * gg[j] + bb[j];
  float4 o0 = make_float4(o[0], o[1], o[2], o[3]);
  float4 o1 = make_float4(o[4], o[5], o[6], o[7]);
  float* q = out + (size_t)row * HID + lane * 8;
  *reinterpret_cast<float4*>(q) = o0;
  *reinterpret_cast<float4*>(q + 4) = o1;
}

// ---------------- softmax(x) pre-pass: row = (t,b,h), 64 wide ----------------
// writes chain-contiguous layout xs[(b*8+h)][t][64] for srec1w streaming
__global__ __launch_bounds__(256) void softmax_x(
    const float* __restrict__ in, float* __restrict__ xs)
{
  const int r = blockIdx.x * 4 + (threadIdx.x >> 6);  // 0..32767
  const int lane = threadIdx.x & 63;
  float v = in[(size_t)r * 64 + lane];
  float m = rmax64(v);
  float e = __expf(v - m);
  float s = rsum64(e);
  float o = e * __builtin_amdgcn_rcpf(s);
  const int t = r >> 7;          // r / (BSZ*NH)
  const int b = (r >> 3) & 15;
  const int h = r & 7;
  xs[(((size_t)(b * 8 + h)) * SLEN + t) * 64 + lane] = o;
}

// ---------------- fast-weight recurrence: ONE wave per (b,h) chain ----------------
// Lane i holds row i of Wy/Wq/Wk (192 VGPRs) + wb row. Zero barriers.
// x-vectors (pre-softmaxed) stream global->LDS via global_load_lds, 32-step
// double-buffered chunks (one vmcnt(0) per chunk). d/k broadcast = one LDS
// roundtrip per step on an exclusive (1 block/CU) LDS.
#define CH 32
#define NCH (SLEN/CH)

__device__ __forceinline__ void stage_chunk(const float* src, float* dst_lds, int lane){
#pragma unroll
  for (int i = 0; i < (CH*64)/256; ++i)   // 8 x 1KB
    __builtin_amdgcn_global_load_lds(
        (const __attribute__((address_space(1))) void*)(src + i*256 + lane*4),
        (__attribute__((address_space(3))) void*)(dst_lds + i*256), 16, 0, 0);
}

__global__ __launch_bounds__(64) void srec1w(
    const float* __restrict__ xs,
    const float* __restrict__ Wy0, const float* __restrict__ Wq0,
    const float* __restrict__ Wk0, const float* __restrict__ wb0,
    float* __restrict__ ys)
{
  const int bh = blockIdx.x;
  const int bb = bh >> 3, hh = bh & 7;
  const int lane = threadIdx.x;

  __shared__ __align__(16) float xls[2][CH*64];   // 2 x 8KB x-chunks
  __shared__ __align__(16) float dkb[128];        // [0..63]=d, [64..127]=k

  float Wy[64], Wq[64], Wk[64];
  float wbr[4];
  {
    const float4* py = reinterpret_cast<const float4*>(Wy0 + (size_t)(hh*64 + lane) * 64);
    const float4* pq = reinterpret_cast<const float4*>(Wq0 + (size_t)(hh*64 + lane) * 64);
    const float4* pk = reinterpret_cast<const float4*>(Wk0 + (size_t)(hh*64 + lane) * 64);
#pragma unroll
    for (int j = 0; j < 16; ++j) {
      float4 a = py[j]; Wy[4*j]=a.x; Wy[4*j+1]=a.y; Wy[4*j+2]=a.z; Wy[4*j+3]=a.w;
      float4 b = pq[j]; Wq[4*j]=b.x; Wq[4*j+1]=b.y; Wq[4*j+2]=b.z; Wq[4*j+3]=b.w;
      float4 c = pk[j]; Wk[4*j]=c.x; Wk[4*j+1]=c.y; Wk[4*j+2]=c.z; Wk[4*j+3]=c.w;
    }
    float4 w = *reinterpret_cast<const float4*>(&wb0[(size_t)(hh*64 + lane) * 4]);
    wbr[0] = w.x; wbr[1] = w.y; wbr[2] = w.z; wbr[3] = w.w;
  }

  const float* xsb = xs + (size_t)bh * SLEN * 64;
  float* yp = ys + (size_t)bb * HID + hh * 64 + lane;

  stage_chunk(xsb, &xls[0][0], lane);
  asm volatile("s_waitcnt vmcnt(0)" ::: "memory");

  int buf = 0;
  for (int c = 0; c < NCH; ++c) {
    if (c + 1 < NCH) stage_chunk(xsb + (size_t)(c+1)*CH*64, &xls[buf^1][0], lane);

    for (int s = 0; s < CH; ++s) {
      const int t = c * CH + s;

      // ---- beta from pre-update wb and this step's x (overlaps phase A) ----
      float xown = xls[buf][s*64 + lane];
      float t0 = rsum64(wbr[0] * xown);
      float t1 = rsum64(wbr[1] * xown);
      float t2 = rsum64(wbr[2] * xown);
      float t3 = rsum64(wbr[3] * xown);
      float beta0 = 1.f / (1.f + __expf(-t0));
      float beta1 = 1.f / (1.f + __expf(-t1));
      float beta2 = 1.f / (1.f + __expf(-t2));
      float beta3 = 1.f / (1.f + __expf(-t3));

      // ---- phase A: y = Wy x, q_raw = Wq x, k_raw = Wk x (x broadcast from LDS) ----
      const float4* xv = reinterpret_cast<const float4*>(&xls[buf][s*64]);
      float ay0=0,ay1=0,ay2=0,ay3=0, aq0=0,aq1=0,aq2=0,aq3=0, ak0=0,ak1=0,ak2=0,ak3=0;
#pragma unroll
      for (int j = 0; j < 16; ++j) {
        float4 x4 = xv[j];
        ay0 = fmaf(Wy[4*j],   x4.x, ay0); ay1 = fmaf(Wy[4*j+1], x4.y, ay1);
        ay2 = fmaf(Wy[4*j+2], x4.z, ay2); ay3 = fmaf(Wy[4*j+3], x4.w, ay3);
        aq0 = fmaf(Wq[4*j],   x4.x, aq0); aq1 = fmaf(Wq[4*j+1], x4.y, aq1);
        aq2 = fmaf(Wq[4*j+2], x4.z, aq2); aq3 = fmaf(Wq[4*j+3], x4.w, aq3);
        ak0 = fmaf(Wk[4*j],   x4.x, ak0); ak1 = fmaf(Wk[4*j+1], x4.y, ak1);
        ak2 = fmaf(Wk[4*j+2], x4.z, ak2); ak3 = fmaf(Wk[4*j+3], x4.w, ak3);
      }
      float ay = (ay0+ay1)+(ay2+ay3);
      float aq = (aq0+aq1)+(aq2+aq3);
      float ak = (ak0+ak1)+(ak2+ak3);

      yp[(size_t)t * BSZ * HID] = ay;   // fire-and-forget

      float mq = rmax64(aq); float eq = __expf(aq - mq); float sq = rsum64(eq);
      float q_l = eq * __builtin_amdgcn_rcpf(sq);
      float mk = rmax64(ak); float ek = __expf(ak - mk); float sk = rsum64(ek);
      float k_l = ek * __builtin_amdgcn_rcpf(sk);
      float d_l = q_l - k_l;

      dkb[lane]      = d_l;
      dkb[64 + lane] = k_l;

      // ---- wb update (lane-local, overlaps the LDS roundtrip) ----
      float e0 = rsum64(wbr[0] * d_l);
      float e1 = rsum64(wbr[1] * d_l);
      float e2 = rsum64(wbr[2] * d_l);
      float e3 = rsum64(wbr[3] * d_l);
      float bk = beta3 * k_l;
      wbr[0] = fmaf(bk, e0, wbr[0]);
      wbr[1] = fmaf(bk, e1, wbr[1]);
      wbr[2] = fmaf(bk, e2, wbr[2]);
      wbr[3] = fmaf(bk, e3, wbr[3]);

      // ---- phase B: dX = WX d ; WX += (betaX*dX_i) * k_j ----
      const float4* dv = reinterpret_cast<const float4*>(&dkb[0]);
      const float4* kv = reinterpret_cast<const float4*>(&dkb[64]);
      float4 karr[16];
      float dy0=0,dy1=0,dy2=0,dy3=0, dq0=0,dq1=0,dq2=0,dq3=0, dk0=0,dk1=0,dk2=0,dk3=0;
#pragma unroll
      for (int j = 0; j < 16; ++j) {
        float4 d4 = dv[j];
        float4 k4 = kv[j];
        karr[j] = k4;
        dy0 = fmaf(Wy[4*j],   d4.x, dy0); dy1 = fmaf(Wy[4*j+1], d4.y, dy1);
        dy2 = fmaf(Wy[4*j+2], d4.z, dy2); dy3 = fmaf(Wy[4*j+3], d4.w, dy3);
        dq0 = fmaf(Wq[4*j],   d4.x, dq0); dq1 = fmaf(Wq[4*j+1], d4.y, dq1);
        dq2 = fmaf(Wq[4*j+2], d4.z, dq2); dq3 = fmaf(Wq[4*j+3], d4.w, dq3);
        dk0 = fmaf(Wk[4*j],   d4.x, dk0); dk1 = fmaf(Wk[4*j+1], d4.y, dk1);
        dk2 = fmaf(Wk[4*j+2], d4.z, dk2); dk3 = fmaf(Wk[4*j+3], d4.w, dk3);
      }
      float dy = (dy0+dy1)+(dy2+dy3);
      float dq = (dq0+dq1)+(dq2+dq3);
      float dk = (dk0+dk1)+(dk2+dk3);
      float cy = beta0 * dy, cq = beta1 * dq, ck = beta2 * dk;
#pragma unroll
      for (int j = 0; j < 16; ++j) {
        float4 k4 = karr[j];
        Wy[4*j]   = fmaf(cy, k4.x, Wy[4*j]);   Wy[4*j+1] = fmaf(cy, k4.y, Wy[4*j+1]);
        Wy[4*j+2] = fmaf(cy, k4.z, Wy[4*j+2]); Wy[4*j+3] = fmaf(cy, k4.w, Wy[4*j+3]);
        Wq[4*j]   = fmaf(cq, k4.x, Wq[4*j]);   Wq[4*j+1] = fmaf(cq, k4.y, Wq[4*j+1]);
        Wq[4*j+2] = fmaf(cq, k4.z, Wq[4*j+2]); Wq[4*j+3] = fmaf(cq, k4.w, Wq[4*j+3]);
        Wk[4*j]   = fmaf(ck, k4.x, Wk[4*j]);   Wk[4*j+1] = fmaf(ck, k4.y, Wk[4*j+1]);
        Wk[4*j+2] = fmaf(ck, k4.z, Wk[4*j+2]); Wk[4*j+3] = fmaf(ck, k4.w, Wk[4*j+3]);
      }
    }

    asm volatile("s_waitcnt vmcnt(0)" ::: "memory");  // next chunk staged + stores drained
    buf ^= 1;
  }
}

extern "C" void kernel_launch(void* const* d_in, const int* in_sizes, int n_in,
                              void* d_out, int out_size, void* d_ws, size_t ws_size,
                              hipStream_t stream)
{
  const float* x     = (const float*)d_in[0];
  const float* in_w  = (const float*)d_in[1];
  const float* in_b  = (const float*)d_in[2];
  const float* Wy    = (const float*)d_in[3];
  const float* Wq    = (const float*)d_in[4];
  const float* Wk    = (const float*)d_in[5];
  const float* wb    = (const float*)d_in[6];
  const float* Wout  = (const float*)d_in[7];
  const float* ln_g  = (const float*)d_in[8];
  const float* ln_b  = (const float*)d_in[9];
  const float* ff_w1 = (const float*)d_in[10];
  const float* ff_b1 = (const float*)d_in[11];
  const float* ff_w2 = (const float*)d_in[12];
  const float* ff_b2 = (const float*)d_in[13];
  float* out = (float*)d_out;

  char* ws = (char*)d_ws;
  float* ys   = (float*)ws;                 // 8MB
  float* ffb  = (float*)(ws + (8u << 20));  // 32MB
  float* ybuf = (float*)(ws + (40u << 20)); // 8MB — shared with xs (disjoint lifetimes)
  float* xsb  = ybuf;                       // softmax(x), [128][256][64] = 8MB

  gemm_mfma<HID, 512, true, false, false><<<dim3(HID/128, MROWS/128), 512, 0, stream>>>(
      x, in_w, in_b, nullptr, out);

  for (int l = 0; l < 2; ++l) {
    softmax_x<<<(SLEN*BSZ*NH)/4, 256, 0, stream>>>(out, xsb);
    srec1w<<<128, 64, 0, stream>>>(xsb,
                                   Wy + (size_t)l * NH * HD * HD,
                                   Wq + (size_t)l * NH * HD * HD,
                                   Wk + (size_t)l * NH * HD * HD,
                                   wb + (size_t)l * NH * HD * 4,
                                   ys);
    gemm_mfma<HID, HID, false, true, false><<<dim3(HID/128, MROWS/128), 512, 0, stream>>>(
        ys, Wout + (size_t)l * HID * HID, nullptr, out, out);
    layernorm_k<<<MROWS, 64, 0, stream>>>(out, ln_g + (size_t)l * HID, ln_b + (size_t)l * HID, ybuf);
    gemm_mfma<FFD, HID, true, false, true><<<dim3(FFD/128, MROWS/128), 512, 0, stream>>>(
        ybuf, ff_w1 + (size_t)l * HID * FFD, ff_b1 + (size_t)l * FFD, nullptr, ffb);
    gemm_mfma<HID, FFD, true, true, false><<<dim3(HID/128, MROWS/128), 512, 0, stream>>>(
        ffb, ff_w2 + (size_t)l * FFD * HID, ff_b2 + (size_t)l * HID, out, out);
  }
}

// Round 2
// 1247.190 us; speedup vs baseline: 1.4203x; 1.4203x over previous
//
#include <hip/hip_runtime.h>
#include <hip/hip_bf16.h>
#include <math.h>

#define SLEN 256
#define BSZ  16
#define NH   8
#define HD   64
#define HID  512
#define FFD  2048
#define MROWS (SLEN*BSZ)   // 4096

typedef __attribute__((ext_vector_type(8))) short short8v;
typedef __attribute__((ext_vector_type(4))) float float4v;
typedef unsigned short ushort_t;

// lgkmcnt-only barrier: LDS visibility without draining vmcnt (keeps global
// prefetch loads in flight across the barrier; __syncthreads would drain them).
#define SYNC_LDS() do { \
  asm volatile("s_waitcnt lgkmcnt(0)" ::: "memory"); \
  __builtin_amdgcn_s_barrier(); \
} while (0)

// ---- all-VALU wave-64 reductions: 4 DPP xor levels + row_bcast15/31 + readlane ----
template<int C> __device__ __forceinline__ float dppf(float x){
  return __int_as_float(__builtin_amdgcn_update_dpp(__float_as_int(x), __float_as_int(x), C, 0xF, 0xF, false));
}

__device__ __forceinline__ float rsum64(float v){
  v += dppf<0xB1>(v);   // xor 1
  v += dppf<0x4E>(v);   // xor 2
  v += dppf<0x141>(v);  // row_half_mirror (xor 4 level)
  v += dppf<0x140>(v);  // row_mirror      (xor 8 level)
  v += __int_as_float(__builtin_amdgcn_update_dpp(0, __float_as_int(v), 0x142, 0xa, 0xF, false)); // bcast15
  v += __int_as_float(__builtin_amdgcn_update_dpp(0, __float_as_int(v), 0x143, 0xc, 0xF, false)); // bcast31
  return __int_as_float(__builtin_amdgcn_readlane(__float_as_int(v), 63));
}

__device__ __forceinline__ float rmax64(float v){
  v = fmaxf(v, dppf<0xB1>(v));
  v = fmaxf(v, dppf<0x4E>(v));
  v = fmaxf(v, dppf<0x141>(v));
  v = fmaxf(v, dppf<0x140>(v));
  v = fmaxf(v, __int_as_float(__builtin_amdgcn_update_dpp((int)0xff800000u, __float_as_int(v), 0x142, 0xa, 0xF, false)));
  v = fmaxf(v, __int_as_float(__builtin_amdgcn_update_dpp((int)0xff800000u, __float_as_int(v), 0x143, 0xc, 0xF, false)));
  return __int_as_float(__builtin_amdgcn_readlane(__float_as_int(v), 63));
}

__device__ __forceinline__ void split_bf16(float f, ushort_t& h, ushort_t& l){
  unsigned u = __float_as_uint(f);
  unsigned r = u + (0x7fffu + ((u >> 16) & 1u));
  h = (ushort_t)(r >> 16);
  float hf = __uint_as_float(((unsigned)h) << 16);
  float lo = f - hf;
  unsigned u2 = __float_as_uint(lo);
  unsigned r2 = u2 + (0x7fffu + ((u2 >> 16) & 1u));
  l = (ushort_t)(r2 >> 16);
}

// ---------------- MFMA GEMM, bf16x3 split (~fp32 accuracy) ----------------
template<int N, int K, bool BIAS, bool RESID, bool RELU>
__global__ __launch_bounds__(512) void gemm_mfma(
    const float* __restrict__ A, const float* __restrict__ B,
    const float* __restrict__ bias, const float* __restrict__ resid,
    float* __restrict__ C)
{
  __shared__ ushort_t Ah[128][40];
  __shared__ ushort_t Al[128][40];
  __shared__ ushort_t Bh[128][40];   // [col][k] (transposed)
  __shared__ ushort_t Bl[128][40];

  const int tid = threadIdx.x;
  const int wv = tid >> 6, lane = tid & 63;
  const int wm = wv >> 2, wn = wv & 3;
  const int l15 = lane & 15, l16 = lane >> 4;
  const int row0 = blockIdx.y * 128, col0 = blockIdx.x * 128;

  const int sar = tid >> 2, sak = (tid & 3) * 8;
  const int sbc = tid & 127, sbk = (tid >> 7) * 8;

  float4v acc[4][2];
#pragma unroll
  for (int i = 0; i < 4; ++i)
#pragma unroll
    for (int n = 0; n < 2; ++n) acc[i][n] = (float4v)(0.f);

  for (int k0 = 0; k0 < K; k0 += 32) {
    {
      const float* ap = &A[(size_t)(row0 + sar) * K + k0 + sak];
      float4 a0 = *reinterpret_cast<const float4*>(ap);
      float4 a1 = *reinterpret_cast<const float4*>(ap + 4);
      float av[8] = {a0.x, a0.y, a0.z, a0.w, a1.x, a1.y, a1.z, a1.w};
      short8v vh, vl;
#pragma unroll
      for (int j = 0; j < 8; ++j) {
        ushort_t h, l; split_bf16(av[j], h, l);
        vh[j] = (short)h; vl[j] = (short)l;
      }
      *reinterpret_cast<short8v*>(&Ah[sar][sak]) = vh;
      *reinterpret_cast<short8v*>(&Al[sar][sak]) = vl;
    }
    {
      float bv[8];
#pragma unroll
      for (int j = 0; j < 8; ++j)
        bv[j] = B[(size_t)(k0 + sbk + j) * N + col0 + sbc];
      short8v vh, vl;
#pragma unroll
      for (int j = 0; j < 8; ++j) {
        ushort_t h, l; split_bf16(bv[j], h, l);
        vh[j] = (short)h; vl[j] = (short)l;
      }
      *reinterpret_cast<short8v*>(&Bh[sbc][sbk]) = vh;
      *reinterpret_cast<short8v*>(&Bl[sbc][sbk]) = vl;
    }
    __syncthreads();

    short8v ah[4], al[4], bh[2], bl[2];
#pragma unroll
    for (int i = 0; i < 4; ++i) {
      const int r = wm * 64 + i * 16 + l15;
      ah[i] = *reinterpret_cast<const short8v*>(&Ah[r][l16 * 8]);
      al[i] = *reinterpret_cast<const short8v*>(&Al[r][l16 * 8]);
    }
#pragma unroll
    for (int n = 0; n < 2; ++n) {
      const int c = wn * 32 + n * 16 + l15;
      bh[n] = *reinterpret_cast<const short8v*>(&Bh[c][l16 * 8]);
      bl[n] = *reinterpret_cast<const short8v*>(&Bl[c][l16 * 8]);
    }
#pragma unroll
    for (int i = 0; i < 4; ++i)
#pragma unroll
      for (int n = 0; n < 2; ++n) {
        acc[i][n] = __builtin_amdgcn_mfma_f32_16x16x32_bf16(ah[i], bh[n], acc[i][n], 0, 0, 0);
        acc[i][n] = __builtin_amdgcn_mfma_f32_16x16x32_bf16(ah[i], bl[n], acc[i][n], 0, 0, 0);
        acc[i][n] = __builtin_amdgcn_mfma_f32_16x16x32_bf16(al[i], bh[n], acc[i][n], 0, 0, 0);
      }
    __syncthreads();
  }

#pragma unroll
  for (int i = 0; i < 4; ++i) {
#pragma unroll
    for (int n = 0; n < 2; ++n) {
      const int col = col0 + wn * 32 + n * 16 + l15;
      float bs = BIAS ? bias[col] : 0.f;
#pragma unroll
      for (int r = 0; r < 4; ++r) {
        const int row = row0 + wm * 64 + i * 16 + l16 * 4 + r;
        float v = acc[i][n][r] + bs;
        if (RESID) v += resid[(size_t)row * N + col];
        if (RELU)  v = fmaxf(v, 0.f);
        C[(size_t)row * N + col] = v;
      }
    }
  }
}

// ---------------- layernorm over HID=512 ----------------
__global__ __launch_bounds__(64) void layernorm_k(
    const float* __restrict__ in, const float* __restrict__ g,
    const float* __restrict__ b, float* __restrict__ out)
{
  const int row = blockIdx.x, lane = threadIdx.x;
  const float* p = in + (size_t)row * HID + lane * 8;
  float4 v0 = *reinterpret_cast<const float4*>(p);
  float4 v1 = *reinterpret_cast<const float4*>(p + 4);
  float s = v0.x + v0.y + v0.z + v0.w + v1.x + v1.y + v1.z + v1.w;
  s = rsum64(s);
  const float mean = s * (1.0f / HID);
  float x[8] = {v0.x, v0.y, v0.z, v0.w, v1.x, v1.y, v1.z, v1.w};
  float sq = 0.f;
#pragma unroll
  for (int j = 0; j < 8; ++j) { float d = x[j] - mean; sq += d * d; }
  sq = rsum64(sq);
  const float rstd = rsqrtf(sq * (1.0f / HID) + 1e-5f);
  float4 g0 = *reinterpret_cast<const float4*>(&g[lane * 8]);
  float4 g1 = *reinterpret_cast<const float4*>(&g[lane * 8 + 4]);
  float4 b0 = *reinterpret_cast<const float4*>(&b[lane * 8]);
  float4 b1 = *reinterpret_cast<const float4*>(&b[lane * 8 + 4]);
  float gg[8] = {g0.x, g0.y, g0.z, g0.w, g1.x, g1.y, g1.z, g1.w};
  float bb[8] = {b0.x, b0.y, b0.z, b0.w, b1.x, b1.y, b1.z, b1.w};
  float o[8];
#pragma unroll
  for (int j = 0; j < 8; ++j) o[j] = (x[j] - mean) * rstd * gg[j] + bb[j];
  float4 o0 = make_float4(o[0], o[1], o[2], o[3]);
  float4 o1 = make_float4(o[4], o[5], o[6], o[7]);
  float* q = out + (size_t)row * HID + lane * 8;
  *reinterpret_cast<float4*>(q) = o0;
  *reinterpret_cast<float4*>(q + 4) = o1;
}

// ---------------- fast-weight recurrence: 2 chains x 4 waves per block ----------------
// Proven srec4 structure (wave0: Wy+y store; wave1: Wq+q softmax; wave2: Wk+k
// softmax; wave3: x prefetch + input softmax + beta/wb) extended to TWO
// independent (b,h) chains per block. 8 waves / 512 threads -> 2 waves per
// SIMD from independent chains, so DPP-reduce / LDS-latency stalls of one
// chain are filled by issue from the other. One lgkmcnt-only barrier per
// phase; global x prefetch loads stay in flight across barriers.
__global__ __launch_bounds__(512) void srec8(
    const float* __restrict__ h,
    const float* __restrict__ Wy0, const float* __restrict__ Wq0,
    const float* __restrict__ Wk0, const float* __restrict__ wb0,
    float* __restrict__ ys)
{
  const int tid = threadIdx.x;
  const int wv8 = tid >> 6, lane = tid & 63;
  const int ch = wv8 >> 2;          // chain within block (0/1)
  const int wv = wv8 & 3;           // role within chain
  const int bh = blockIdx.x * 2 + ch;
  const int bb = bh >> 3, hh = bh & 7;

  __shared__ float xs[2][2][64];     // [ch][phase][lane]
  __shared__ float q_s[2][2][64];
  __shared__ float k_s[2][2][64];
  __shared__ float4 betas4[2][2];    // [ch][phase]

  float W[64];
  float wbr[4] = {0.f, 0.f, 0.f, 0.f};
  float xrA = 0.f, xrB = 0.f;   // raw-x prefetch registers (alternating)
  float xnreg = 0.f;            // softmax(x(t+1)), carried phase A -> phase B

  const float* xp = h + (size_t)bb * HID + hh * 64 + lane;
  float* yp = ys + (size_t)bb * HID + hh * 64 + lane;

  if (wv < 3) {
    const float* base = (wv == 0 ? Wy0 : (wv == 1 ? Wq0 : Wk0)) + (size_t)(hh * 64 + lane) * 64;
#pragma unroll
    for (int j = 0; j < 16; ++j) {
      float4 a = reinterpret_cast<const float4*>(base)[j];
      W[4*j] = a.x; W[4*j+1] = a.y; W[4*j+2] = a.z; W[4*j+3] = a.w;
    }
  } else {
    float4 w = *reinterpret_cast<const float4*>(&wb0[(size_t)(hh * 64 + lane) * 4]);
    wbr[0] = w.x; wbr[1] = w.y; wbr[2] = w.z; wbr[3] = w.w;
    float xr0 = xp[0];
    xrA = xp[(size_t)BSZ * HID];       // raw x(1)
    // softmax(x(0)) -> xs[ch][0]
    float m = rmax64(xr0);
    float e = __expf(xr0 - m);
    float sm = rsum64(e);
    float x0 = e * __builtin_amdgcn_rcpf(sm);
    xs[ch][0][lane] = x0;
    // betas for step 0
    float s0 = rsum64(wbr[0] * x0);
    float s1 = rsum64(wbr[1] * x0);
    float s2 = rsum64(wbr[2] * x0);
    float s3 = rsum64(wbr[3] * x0);
    if (lane == 0)
      betas4[ch][0] = make_float4(1.f / (1.f + __expf(-s0)), 1.f / (1.f + __expf(-s1)),
                                  1.f / (1.f + __expf(-s2)), 1.f / (1.f + __expf(-s3)));
  }
  SYNC_LDS();

  auto stepf = [&](int P, float& XCUR, float& XNEXT, int T) {
    // ---------- phase A ----------
    if (wv == 3) {
      if (T + 2 < SLEN) XNEXT = xp[(size_t)(T + 2) * BSZ * HID];  // issue; used next step
      // softmax of raw x(T+1) -> xs[ch][1-P]
      float m = rmax64(XCUR);
      float e = __expf(XCUR - m);
      float sm = rsum64(e);
      float xn_ = e * __builtin_amdgcn_rcpf(sm);
      xs[ch][1 - P][lane] = xn_;
      xnreg = xn_;
    } else {
      const float4* xv = reinterpret_cast<const float4*>(xs[ch][P]);
      float a0 = 0.f, a1 = 0.f, a2 = 0.f, a3 = 0.f;
#pragma unroll
      for (int j = 0; j < 16; ++j) {
        float4 xx = xv[j];
        a0 = fmaf(W[4*j],   xx.x, a0);
        a1 = fmaf(W[4*j+1], xx.y, a1);
        a2 = fmaf(W[4*j+2], xx.z, a2);
        a3 = fmaf(W[4*j+3], xx.w, a3);
      }
      float acc = (a0 + a1) + (a2 + a3);
      if (wv == 0) {
        yp[(size_t)T * BSZ * HID] = acc;   // fire-and-forget store
      } else {
        float m = rmax64(acc);
        float e = __expf(acc - m);
        float sm = rsum64(e);
        float v = e * __builtin_amdgcn_rcpf(sm);
        float* dst = (wv == 1) ? q_s[ch][P] : k_s[ch][P];
        dst[lane] = v;
      }
    }

    SYNC_LDS();

    // ---------- phase B ----------
    float4 bb4 = betas4[ch][P];
    if (wv < 3) {
      const float4* qv = reinterpret_cast<const float4*>(q_s[ch][P]);
      const float4* kv = reinterpret_cast<const float4*>(k_s[ch][P]);
      float a0 = 0.f, a1 = 0.f, a2 = 0.f, a3 = 0.f;
#pragma unroll
      for (int j = 0; j < 16; ++j) {
        float4 q4 = qv[j], k4 = kv[j];
        a0 = fmaf(W[4*j],   q4.x - k4.x, a0);
        a1 = fmaf(W[4*j+1], q4.y - k4.y, a1);
        a2 = fmaf(W[4*j+2], q4.z - k4.z, a2);
        a3 = fmaf(W[4*j+3], q4.w - k4.w, a3);
      }
      float dd = (a0 + a1) + (a2 + a3);
      float beta = (wv == 0) ? bb4.x : (wv == 1 ? bb4.y : bb4.z);
      float c = beta * dd;
#pragma unroll
      for (int j = 0; j < 16; ++j) {
        float4 k4 = kv[j];
        W[4*j]   = fmaf(c, k4.x, W[4*j]);
        W[4*j+1] = fmaf(c, k4.y, W[4*j+1]);
        W[4*j+2] = fmaf(c, k4.z, W[4*j+2]);
        W[4*j+3] = fmaf(c, k4.w, W[4*j+3]);
      }
    } else {
      // wb update (step T), then betas for step T+1 from updated wbr and xnreg
      float ql = q_s[ch][P][lane], kl = k_s[ch][P][lane];
      float dl = ql - kl;
      float d0 = rsum64(wbr[0] * dl);
      float d1 = rsum64(wbr[1] * dl);
      float d2 = rsum64(wbr[2] * dl);
      float d3 = rsum64(wbr[3] * dl);
      float bk = bb4.w * kl;
      wbr[0] = fmaf(bk, d0, wbr[0]);
      wbr[1] = fmaf(bk, d1, wbr[1]);
      wbr[2] = fmaf(bk, d2, wbr[2]);
      wbr[3] = fmaf(bk, d3, wbr[3]);
      float s0 = rsum64(wbr[0] * xnreg);
      float s1 = rsum64(wbr[1] * xnreg);
      float s2 = rsum64(wbr[2] * xnreg);
      float s3 = rsum64(wbr[3] * xnreg);
      if (lane == 0)
        betas4[ch][1 - P] = make_float4(1.f / (1.f + __expf(-s0)), 1.f / (1.f + __expf(-s1)),
                                        1.f / (1.f + __expf(-s2)), 1.f / (1.f + __expf(-s3)));
    }
  };

  for (int t = 0; t < SLEN; t += 2) {
    stepf(0, xrA, xrB, t);
    stepf(1, xrB, xrA, t + 1);
  }
}

extern "C" void kernel_launch(void* const* d_in, const int* in_sizes, int n_in,
                              void* d_out, int out_size, void* d_ws, size_t ws_size,
                              hipStream_t stream)
{
  const float* x     = (const float*)d_in[0];
  const float* in_w  = (const float*)d_in[1];
  const float* in_b  = (const float*)d_in[2];
  const float* Wy    = (const float*)d_in[3];
  const float* Wq    = (const float*)d_in[4];
  const float* Wk    = (const float*)d_in[5];
  const float* wb    = (const float*)d_in[6];
  const float* Wout  = (const float*)d_in[7];
  const float* ln_g  = (const float*)d_in[8];
  const float* ln_b  = (const float*)d_in[9];
  const float* ff_w1 = (const float*)d_in[10];
  const float* ff_b1 = (const float*)d_in[11];
  const float* ff_w2 = (const float*)d_in[12];
  const float* ff_b2 = (const float*)d_in[13];
  float* out = (float*)d_out;

  char* ws = (char*)d_ws;
  float* ys   = (float*)ws;                 // 8MB
  float* ffb  = (float*)(ws + (8u << 20));  // 32MB
  float* ybuf = (float*)(ws + (40u << 20)); // 8MB

  gemm_mfma<HID, 512, true, false, false><<<dim3(HID/128, MROWS/128), 512, 0, stream>>>(
      x, in_w, in_b, nullptr, out);

  for (int l = 0; l < 2; ++l) {
    srec8<<<64, 512, 0, stream>>>(out,
                                  Wy + (size_t)l * NH * HD * HD,
                                  Wq + (size_t)l * NH * HD * HD,
                                  Wk + (size_t)l * NH * HD * HD,
                                  wb + (size_t)l * NH * HD * 4,
                                  ys);
    gemm_mfma<HID, HID, false, true, false><<<dim3(HID/128, MROWS/128), 512, 0, stream>>>(
        ys, Wout + (size_t)l * HID * HID, nullptr, out, out);
    layernorm_k<<<MROWS, 64, 0, stream>>>(out, ln_g + (size_t)l * HID, ln_b + (size_t)l * HID, ybuf);
    gemm_mfma<FFD, HID, true, false, true><<<dim3(FFD/128, MROWS/128), 512, 0, stream>>>(
        ybuf, ff_w1 + (size_t)l * HID * FFD, ff_b1 + (size_t)l * FFD, nullptr, ffb);
    gemm_mfma<HID, FFD, true, true, false><<<dim3(HID/128, MROWS/128), 512, 0, stream>>>(
        ffb, ff_w2 + (size_t)l * FFD * HID, ff_b2 + (size_t)l * HID, out, out);
  }
}

// Round 3
// 1103.468 us; speedup vs baseline: 1.6053x; 1.1302x over previous
//
#include <hip/hip_runtime.h>
#include <hip/hip_bf16.h>
#include <math.h>

#define SLEN 256
#define BSZ  16
#define NH   8
#define HD   64
#define HID  512
#define FFD  2048
#define MROWS (SLEN*BSZ)   // 4096

typedef __attribute__((ext_vector_type(8))) short short8v;
typedef __attribute__((ext_vector_type(4))) float float4v;
typedef unsigned short ushort_t;

// lgkmcnt-only barrier: LDS visibility without draining vmcnt (keeps global
// prefetch loads in flight across the barrier; __syncthreads would drain them).
#define SYNC_LDS() do { \
  asm volatile("s_waitcnt lgkmcnt(0)" ::: "memory"); \
  __builtin_amdgcn_s_barrier(); \
} while (0)

// ---- all-VALU wave-64 reductions: 4 DPP xor levels + row_bcast15/31 + readlane ----
template<int C> __device__ __forceinline__ float dppf(float x){
  return __int_as_float(__builtin_amdgcn_update_dpp(__float_as_int(x), __float_as_int(x), C, 0xF, 0xF, false));
}

__device__ __forceinline__ float rsum64(float v){
  v += dppf<0xB1>(v);   // xor 1
  v += dppf<0x4E>(v);   // xor 2
  v += dppf<0x141>(v);  // row_half_mirror (xor 4 level)
  v += dppf<0x140>(v);  // row_mirror      (xor 8 level)
  v += __int_as_float(__builtin_amdgcn_update_dpp(0, __float_as_int(v), 0x142, 0xa, 0xF, false)); // bcast15
  v += __int_as_float(__builtin_amdgcn_update_dpp(0, __float_as_int(v), 0x143, 0xc, 0xF, false)); // bcast31
  return __int_as_float(__builtin_amdgcn_readlane(__float_as_int(v), 63));
}

__device__ __forceinline__ float rmax64(float v){
  v = fmaxf(v, dppf<0xB1>(v));
  v = fmaxf(v, dppf<0x4E>(v));
  v = fmaxf(v, dppf<0x141>(v));
  v = fmaxf(v, dppf<0x140>(v));
  v = fmaxf(v, __int_as_float(__builtin_amdgcn_update_dpp((int)0xff800000u, __float_as_int(v), 0x142, 0xa, 0xF, false)));
  v = fmaxf(v, __int_as_float(__builtin_amdgcn_update_dpp((int)0xff800000u, __float_as_int(v), 0x143, 0xc, 0xF, false)));
  return __int_as_float(__builtin_amdgcn_readlane(__float_as_int(v), 63));
}

__device__ __forceinline__ void split_bf16(float f, ushort_t& h, ushort_t& l){
  unsigned u = __float_as_uint(f);
  unsigned r = u + (0x7fffu + ((u >> 16) & 1u));
  h = (ushort_t)(r >> 16);
  float hf = __uint_as_float(((unsigned)h) << 16);
  float lo = f - hf;
  unsigned u2 = __float_as_uint(lo);
  unsigned r2 = u2 + (0x7fffu + ((u2 >> 16) & 1u));
  l = (ushort_t)(r2 >> 16);
}

// ---------------- MFMA GEMM, bf16x3 split (~fp32 accuracy) ----------------
template<int N, int K, bool BIAS, bool RESID, bool RELU>
__global__ __launch_bounds__(512) void gemm_mfma(
    const float* __restrict__ A, const float* __restrict__ B,
    const float* __restrict__ bias, const float* __restrict__ resid,
    float* __restrict__ C)
{
  __shared__ ushort_t Ah[128][40];
  __shared__ ushort_t Al[128][40];
  __shared__ ushort_t Bh[128][40];   // [col][k] (transposed)
  __shared__ ushort_t Bl[128][40];

  const int tid = threadIdx.x;
  const int wv = tid >> 6, lane = tid & 63;
  const int wm = wv >> 2, wn = wv & 3;
  const int l15 = lane & 15, l16 = lane >> 4;
  const int row0 = blockIdx.y * 128, col0 = blockIdx.x * 128;

  const int sar = tid >> 2, sak = (tid & 3) * 8;
  const int sbc = tid & 127, sbk = (tid >> 7) * 8;

  float4v acc[4][2];
#pragma unroll
  for (int i = 0; i < 4; ++i)
#pragma unroll
    for (int n = 0; n < 2; ++n) acc[i][n] = (float4v)(0.f);

  for (int k0 = 0; k0 < K; k0 += 32) {
    {
      const float* ap = &A[(size_t)(row0 + sar) * K + k0 + sak];
      float4 a0 = *reinterpret_cast<const float4*>(ap);
      float4 a1 = *reinterpret_cast<const float4*>(ap + 4);
      float av[8] = {a0.x, a0.y, a0.z, a0.w, a1.x, a1.y, a1.z, a1.w};
      short8v vh, vl;
#pragma unroll
      for (int j = 0; j < 8; ++j) {
        ushort_t h, l; split_bf16(av[j], h, l);
        vh[j] = (short)h; vl[j] = (short)l;
      }
      *reinterpret_cast<short8v*>(&Ah[sar][sak]) = vh;
      *reinterpret_cast<short8v*>(&Al[sar][sak]) = vl;
    }
    {
      float bv[8];
#pragma unroll
      for (int j = 0; j < 8; ++j)
        bv[j] = B[(size_t)(k0 + sbk + j) * N + col0 + sbc];
      short8v vh, vl;
#pragma unroll
      for (int j = 0; j < 8; ++j) {
        ushort_t h, l; split_bf16(bv[j], h, l);
        vh[j] = (short)h; vl[j] = (short)l;
      }
      *reinterpret_cast<short8v*>(&Bh[sbc][sbk]) = vh;
      *reinterpret_cast<short8v*>(&Bl[sbc][sbk]) = vl;
    }
    __syncthreads();

    short8v ah[4], al[4], bh[2], bl[2];
#pragma unroll
    for (int i = 0; i < 4; ++i) {
      const int r = wm * 64 + i * 16 + l15;
      ah[i] = *reinterpret_cast<const short8v*>(&Ah[r][l16 * 8]);
      al[i] = *reinterpret_cast<const short8v*>(&Al[r][l16 * 8]);
    }
#pragma unroll
    for (int n = 0; n < 2; ++n) {
      const int c = wn * 32 + n * 16 + l15;
      bh[n] = *reinterpret_cast<const short8v*>(&Bh[c][l16 * 8]);
      bl[n] = *reinterpret_cast<const short8v*>(&Bl[c][l16 * 8]);
    }
#pragma unroll
    for (int i = 0; i < 4; ++i)
#pragma unroll
      for (int n = 0; n < 2; ++n) {
        acc[i][n] = __builtin_amdgcn_mfma_f32_16x16x32_bf16(ah[i], bh[n], acc[i][n], 0, 0, 0);
        acc[i][n] = __builtin_amdgcn_mfma_f32_16x16x32_bf16(ah[i], bl[n], acc[i][n], 0, 0, 0);
        acc[i][n] = __builtin_amdgcn_mfma_f32_16x16x32_bf16(al[i], bh[n], acc[i][n], 0, 0, 0);
      }
    __syncthreads();
  }

#pragma unroll
  for (int i = 0; i < 4; ++i) {
#pragma unroll
    for (int n = 0; n < 2; ++n) {
      const int col = col0 + wn * 32 + n * 16 + l15;
      float bs = BIAS ? bias[col] : 0.f;
#pragma unroll
      for (int r = 0; r < 4; ++r) {
        const int row = row0 + wm * 64 + i * 16 + l16 * 4 + r;
        float v = acc[i][n][r] + bs;
        if (RESID) v += resid[(size_t)row * N + col];
        if (RELU)  v = fmaxf(v, 0.f);
        C[(size_t)row * N + col] = v;
      }
    }
  }
}

// ---------------- layernorm over HID=512 ----------------
__global__ __launch_bounds__(64) void layernorm_k(
    const float* __restrict__ in, const float* __restrict__ g,
    const float* __restrict__ b, float* __restrict__ out)
{
  const int row = blockIdx.x, lane = threadIdx.x;
  const float* p = in + (size_t)row * HID + lane * 8;
  float4 v0 = *reinterpret_cast<const float4*>(p);
  float4 v1 = *reinterpret_cast<const float4*>(p + 4);
  float s = v0.x + v0.y + v0.z + v0.w + v1.x + v1.y + v1.z + v1.w;
  s = rsum64(s);
  const float mean = s * (1.0f / HID);
  float x[8] = {v0.x, v0.y, v0.z, v0.w, v1.x, v1.y, v1.z, v1.w};
  float sq = 0.f;
#pragma unroll
  for (int j = 0; j < 8; ++j) { float d = x[j] - mean; sq += d * d; }
  sq = rsum64(sq);
  const float rstd = rsqrtf(sq * (1.0f / HID) + 1e-5f);
  float4 g0 = *reinterpret_cast<const float4*>(&g[lane * 8]);
  float4 g1 = *reinterpret_cast<const float4*>(&g[lane * 8 + 4]);
  float4 b0 = *reinterpret_cast<const float4*>(&b[lane * 8]);
  float4 b1 = *reinterpret_cast<const float4*>(&b[lane * 8 + 4]);
  float gg[8] = {g0.x, g0.y, g0.z, g0.w, g1.x, g1.y, g1.z, g1.w};
  float bb[8] = {b0.x, b0.y, b0.z, b0.w, b1.x, b1.y, b1.z, b1.w};
  float o[8];
#pragma unroll
  for (int j = 0; j < 8; ++j) o[j] = (x[j] - mean) * rstd * gg[j] + bb[j];
  float4 o0 = make_float4(o[0], o[1], o[2], o[3]);
  float4 o1 = make_float4(o[4], o[5], o[6], o[7]);
  float* q = out + (size_t)row * HID + lane * 8;
  *reinterpret_cast<float4*>(q) = o0;
  *reinterpret_cast<float4*>(q + 4) = o1;
}

// ---------------- fast-weight recurrence: 4 waves per (b,h) chain ----------------
// srec4 + rank-1 "lazy matvec": a_t = W_{t-1} x_t + beta_{t-1} (k_{t-1}.x_t) v_{t-1}
// (exact identity, W_t = W_{t-1} + beta v k^T). The W_{t-1} x_t "shadow" matvec is
// computed in phase B(t-1), overlapping the q/k LDS-read latency; the dot
// g = k.x_next is free in wave3 (both operands lane-local registers). Phase A
// for W-waves collapses to 1 uniform LDS read + 2 FMA + softmax. 2 barriers/step.
__global__ __launch_bounds__(256) void srec4s(
    const float* __restrict__ h,
    const float* __restrict__ Wy0, const float* __restrict__ Wq0,
    const float* __restrict__ Wk0, const float* __restrict__ wb0,
    float* __restrict__ ys)
{
  const int bh = blockIdx.x;
  const int bb = bh >> 3, hh = bh & 7;
  const int tid = threadIdx.x;
  const int wv = tid >> 6, lane = tid & 63;

  __shared__ float xs[2][64];
  __shared__ float q_s[2][64];
  __shared__ float k_s[2][64];
  __shared__ float4 betas4[2];
  __shared__ float gdot[2];      // k_t . x_{t+1}, published by wave3 in phase B

  float W[64];
  float wbr[4] = {0.f, 0.f, 0.f, 0.f};
  float xrA = 0.f, xrB = 0.f;   // raw-x prefetch registers (alternating)
  float xnreg = 0.f;            // softmax(x(t+1)), carried phase A -> phase B
  float shadow = 0.f;           // W_{t-1} x_t, computed one step early
  float v_prev = 0.f;           // dW_{t-1} (lane-local component)
  float c_prev = 0.f;           // beta_{t-1} (this wave's component)

  const float* xp = h + (size_t)bb * HID + hh * 64 + lane;
  float* yp = ys + (size_t)bb * HID + hh * 64 + lane;

  if (wv < 3) {
    const float* base = (wv == 0 ? Wy0 : (wv == 1 ? Wq0 : Wk0)) + (size_t)(hh * 64 + lane) * 64;
#pragma unroll
    for (int j = 0; j < 16; ++j) {
      float4 a = reinterpret_cast<const float4*>(base)[j];
      W[4*j] = a.x; W[4*j+1] = a.y; W[4*j+2] = a.z; W[4*j+3] = a.w;
    }
  } else {
    float4 w = *reinterpret_cast<const float4*>(&wb0[(size_t)(hh * 64 + lane) * 4]);
    wbr[0] = w.x; wbr[1] = w.y; wbr[2] = w.z; wbr[3] = w.w;
    float xr0 = xp[0];
    xrA = xp[(size_t)BSZ * HID];       // raw x(1)
    // softmax(x(0)) -> xs[0]
    float m = rmax64(xr0);
    float e = __expf(xr0 - m);
    float sm = rsum64(e);
    float x0 = e * __builtin_amdgcn_rcpf(sm);
    xs[0][lane] = x0;
    // betas for step 0
    float s0 = rsum64(wbr[0] * x0);
    float s1 = rsum64(wbr[1] * x0);
    float s2 = rsum64(wbr[2] * x0);
    float s3 = rsum64(wbr[3] * x0);
    if (lane == 0) {
      betas4[0] = make_float4(1.f / (1.f + __expf(-s0)), 1.f / (1.f + __expf(-s1)),
                              1.f / (1.f + __expf(-s2)), 1.f / (1.f + __expf(-s3)));
      gdot[0] = 0.f; gdot[1] = 0.f;
    }
  }
  SYNC_LDS();

  // prologue shadow: shadow_0 = W x_0 (same-wave dependency, no barrier needed)
  if (wv < 3) {
    const float4* xv = reinterpret_cast<const float4*>(xs[0]);
    float s0 = 0.f, s1 = 0.f, s2 = 0.f, s3 = 0.f;
#pragma unroll
    for (int j = 0; j < 16; ++j) {
      float4 x4 = xv[j];
      s0 = fmaf(W[4*j],   x4.x, s0);
      s1 = fmaf(W[4*j+1], x4.y, s1);
      s2 = fmaf(W[4*j+2], x4.z, s2);
      s3 = fmaf(W[4*j+3], x4.w, s3);
    }
    shadow = (s0 + s1) + (s2 + s3);
  }

  auto stepf = [&](int P, float& XCUR, float& XNEXT, int T) {
    // ---------- phase A ----------
    if (wv == 3) {
      if (T + 2 < SLEN) XNEXT = xp[(size_t)(T + 2) * BSZ * HID];  // issue; used next step
      // softmax of raw x(T+1) -> xs[1-P]
      float m = rmax64(XCUR);
      float e = __expf(XCUR - m);
      float sm = rsum64(e);
      float xn_ = e * __builtin_amdgcn_rcpf(sm);
      xs[1 - P][lane] = xn_;
      xnreg = xn_;
    } else {
      // a_t = shadow + beta_{t-1} * (k_{t-1}.x_t) * v_prev   (rank-1 lazy correction)
      float acc = fmaf(c_prev * gdot[P], v_prev, shadow);
      if (wv == 0) {
        yp[(size_t)T * BSZ * HID] = acc;   // fire-and-forget store
      } else {
        float m = rmax64(acc);
        float e = __expf(acc - m);
        float sm = rsum64(e);
        float v = e * __builtin_amdgcn_rcpf(sm);
        float* dst = (wv == 1) ? q_s[P] : k_s[P];
        dst[lane] = v;
      }
    }

    SYNC_LDS();

    // ---------- phase B ----------
    float4 bb4 = betas4[P];
    if (wv < 3) {
      const float4* qv = reinterpret_cast<const float4*>(q_s[P]);
      const float4* kv = reinterpret_cast<const float4*>(k_s[P]);
      const float4* xv = reinterpret_cast<const float4*>(xs[1 - P]);  // x_{t+1}
      float4 karr[16];
      float a0 = 0.f, a1 = 0.f, a2 = 0.f, a3 = 0.f;   // dW = W d accum
      float s0 = 0.f, s1 = 0.f, s2 = 0.f, s3 = 0.f;   // shadow = W x_{t+1} accum (pre-update W)
#pragma unroll
      for (int j = 0; j < 16; ++j) {
        float4 q4 = qv[j], k4 = kv[j], x4 = xv[j];
        karr[j] = k4;
        a0 = fmaf(W[4*j],   q4.x - k4.x, a0);
        a1 = fmaf(W[4*j+1], q4.y - k4.y, a1);
        a2 = fmaf(W[4*j+2], q4.z - k4.z, a2);
        a3 = fmaf(W[4*j+3], q4.w - k4.w, a3);
        s0 = fmaf(W[4*j],   x4.x, s0);
        s1 = fmaf(W[4*j+1], x4.y, s1);
        s2 = fmaf(W[4*j+2], x4.z, s2);
        s3 = fmaf(W[4*j+3], x4.w, s3);
      }
      float dd = (a0 + a1) + (a2 + a3);
      shadow = (s0 + s1) + (s2 + s3);
      float beta = (wv == 0) ? bb4.x : (wv == 1 ? bb4.y : bb4.z);
      float c = beta * dd;
#pragma unroll
      for (int j = 0; j < 16; ++j) {
        float4 k4 = karr[j];
        W[4*j]   = fmaf(c, k4.x, W[4*j]);
        W[4*j+1] = fmaf(c, k4.y, W[4*j+1]);
        W[4*j+2] = fmaf(c, k4.z, W[4*j+2]);
        W[4*j+3] = fmaf(c, k4.w, W[4*j+3]);
      }
      v_prev = dd;
      c_prev = beta;
    } else {
      // wb update (step T), then betas for step T+1, plus g = k_t . x_{t+1}
      float ql = q_s[P][lane], kl = k_s[P][lane];
      float dl = ql - kl;
      float d0 = rsum64(wbr[0] * dl);
      float d1 = rsum64(wbr[1] * dl);
      float d2 = rsum64(wbr[2] * dl);
      float d3 = rsum64(wbr[3] * dl);
      float g  = rsum64(kl * xnreg);          // k_t . x_{t+1} (both lane-local)
      float bk = bb4.w * kl;
      wbr[0] = fmaf(bk, d0, wbr[0]);
      wbr[1] = fmaf(bk, d1, wbr[1]);
      wbr[2] = fmaf(bk, d2, wbr[2]);
      wbr[3] = fmaf(bk, d3, wbr[3]);
      float s0 = rsum64(wbr[0] * xnreg);
      float s1 = rsum64(wbr[1] * xnreg);
      float s2 = rsum64(wbr[2] * xnreg);
      float s3 = rsum64(wbr[3] * xnreg);
      if (lane == 0) {
        betas4[1 - P] = make_float4(1.f / (1.f + __expf(-s0)), 1.f / (1.f + __expf(-s1)),
                                    1.f / (1.f + __expf(-s2)), 1.f / (1.f + __expf(-s3)));
        gdot[1 - P] = g;
      }
    }

    SYNC_LDS();   // protects gdot/betas (written B) + xs WAR for next step
  };

  for (int t = 0; t < SLEN; t += 2) {
    stepf(0, xrA, xrB, t);
    stepf(1, xrB, xrA, t + 1);
  }
}

extern "C" void kernel_launch(void* const* d_in, const int* in_sizes, int n_in,
                              void* d_out, int out_size, void* d_ws, size_t ws_size,
                              hipStream_t stream)
{
  const float* x     = (const float*)d_in[0];
  const float* in_w  = (const float*)d_in[1];
  const float* in_b  = (const float*)d_in[2];
  const float* Wy    = (const float*)d_in[3];
  const float* Wq    = (const float*)d_in[4];
  const float* Wk    = (const float*)d_in[5];
  const float* wb    = (const float*)d_in[6];
  const float* Wout  = (const float*)d_in[7];
  const float* ln_g  = (const float*)d_in[8];
  const float* ln_b  = (const float*)d_in[9];
  const float* ff_w1 = (const float*)d_in[10];
  const float* ff_b1 = (const float*)d_in[11];
  const float* ff_w2 = (const float*)d_in[12];
  const float* ff_b2 = (const float*)d_in[13];
  float* out = (float*)d_out;

  char* ws = (char*)d_ws;
  float* ys   = (float*)ws;                 // 8MB
  float* ffb  = (float*)(ws + (8u << 20));  // 32MB
  float* ybuf = (float*)(ws + (40u << 20)); // 8MB

  gemm_mfma<HID, 512, true, false, false><<<dim3(HID/128, MROWS/128), 512, 0, stream>>>(
      x, in_w, in_b, nullptr, out);

  for (int l = 0; l < 2; ++l) {
    srec4s<<<128, 256, 0, stream>>>(out,
                                    Wy + (size_t)l * NH * HD * HD,
                                    Wq + (size_t)l * NH * HD * HD,
                                    Wk + (size_t)l * NH * HD * HD,
                                    wb + (size_t)l * NH * HD * 4,
                                    ys);
    gemm_mfma<HID, HID, false, true, false><<<dim3(HID/128, MROWS/128), 512, 0, stream>>>(
        ys, Wout + (size_t)l * HID * HID, nullptr, out, out);
    layernorm_k<<<MROWS, 64, 0, stream>>>(out, ln_g + (size_t)l * HID, ln_b + (size_t)l * HID, ybuf);
    gemm_mfma<FFD, HID, true, false, true><<<dim3(FFD/128, MROWS/128), 512, 0, stream>>>(
        ybuf, ff_w1 + (size_t)l * HID * FFD, ff_b1 + (size_t)l * FFD, nullptr, ffb);
    gemm_mfma<HID, FFD, true, true, false><<<dim3(HID/128, MROWS/128), 512, 0, stream>>>(
        ffb, ff_w2 + (size_t)l * FFD * HID, ff_b2 + (size_t)l * HID, out, out);
  }
}

// Round 4
// 1013.379 us; speedup vs baseline: 1.7480x; 1.0889x over previous
//
#include <hip/hip_runtime.h>
#include <hip/hip_bf16.h>
#include <math.h>

#define SLEN 256
#define BSZ  16
#define NH   8
#define HD   64
#define HID  512
#define FFD  2048
#define MROWS (SLEN*BSZ)   // 4096

typedef __attribute__((ext_vector_type(8))) short short8v;
typedef __attribute__((ext_vector_type(4))) float float4v;
typedef unsigned short ushort_t;

// lgkmcnt-only barrier: LDS visibility without draining vmcnt (keeps global
// prefetch loads in flight across the barrier; __syncthreads would drain them).
#define SYNC_LDS() do { \
  asm volatile("s_waitcnt lgkmcnt(0)" ::: "memory"); \
  __builtin_amdgcn_s_barrier(); \
} while (0)

// ---- all-VALU wave-64 reductions: 4 DPP xor levels + row_bcast15/31 + readlane ----
template<int C> __device__ __forceinline__ float dppf(float x){
  return __int_as_float(__builtin_amdgcn_update_dpp(__float_as_int(x), __float_as_int(x), C, 0xF, 0xF, false));
}

__device__ __forceinline__ float rsum64(float v){
  v += dppf<0xB1>(v);   // xor 1
  v += dppf<0x4E>(v);   // xor 2
  v += dppf<0x141>(v);  // row_half_mirror (xor 4 level)
  v += dppf<0x140>(v);  // row_mirror      (xor 8 level)
  v += __int_as_float(__builtin_amdgcn_update_dpp(0, __float_as_int(v), 0x142, 0xa, 0xF, false)); // bcast15
  v += __int_as_float(__builtin_amdgcn_update_dpp(0, __float_as_int(v), 0x143, 0xc, 0xF, false)); // bcast31
  return __int_as_float(__builtin_amdgcn_readlane(__float_as_int(v), 63));
}

__device__ __forceinline__ float rmax64(float v){
  v = fmaxf(v, dppf<0xB1>(v));
  v = fmaxf(v, dppf<0x4E>(v));
  v = fmaxf(v, dppf<0x141>(v));
  v = fmaxf(v, dppf<0x140>(v));
  v = fmaxf(v, __int_as_float(__builtin_amdgcn_update_dpp((int)0xff800000u, __float_as_int(v), 0x142, 0xa, 0xF, false)));
  v = fmaxf(v, __int_as_float(__builtin_amdgcn_update_dpp((int)0xff800000u, __float_as_int(v), 0x143, 0xc, 0xF, false)));
  return __int_as_float(__builtin_amdgcn_readlane(__float_as_int(v), 63));
}

// broadcast lane j (compile-time) of v to all lanes via SGPR — VALU pipe, no LDS
__device__ __forceinline__ float rlf(float v, int j){
  return __int_as_float(__builtin_amdgcn_readlane(__float_as_int(v), j));
}

__device__ __forceinline__ void split_bf16(float f, ushort_t& h, ushort_t& l){
  unsigned u = __float_as_uint(f);
  unsigned r = u + (0x7fffu + ((u >> 16) & 1u));
  h = (ushort_t)(r >> 16);
  float hf = __uint_as_float(((unsigned)h) << 16);
  float lo = f - hf;
  unsigned u2 = __float_as_uint(lo);
  unsigned r2 = u2 + (0x7fffu + ((u2 >> 16) & 1u));
  l = (ushort_t)(r2 >> 16);
}

// ---------------- MFMA GEMM, bf16x3 split (~fp32 accuracy) ----------------
template<int N, int K, bool BIAS, bool RESID, bool RELU>
__global__ __launch_bounds__(512) void gemm_mfma(
    const float* __restrict__ A, const float* __restrict__ B,
    const float* __restrict__ bias, const float* __restrict__ resid,
    float* __restrict__ C)
{
  __shared__ ushort_t Ah[128][40];
  __shared__ ushort_t Al[128][40];
  __shared__ ushort_t Bh[128][40];   // [col][k] (transposed)
  __shared__ ushort_t Bl[128][40];

  const int tid = threadIdx.x;
  const int wv = tid >> 6, lane = tid & 63;
  const int wm = wv >> 2, wn = wv & 3;
  const int l15 = lane & 15, l16 = lane >> 4;
  const int row0 = blockIdx.y * 128, col0 = blockIdx.x * 128;

  const int sar = tid >> 2, sak = (tid & 3) * 8;
  const int sbc = tid & 127, sbk = (tid >> 7) * 8;

  float4v acc[4][2];
#pragma unroll
  for (int i = 0; i < 4; ++i)
#pragma unroll
    for (int n = 0; n < 2; ++n) acc[i][n] = (float4v)(0.f);

  for (int k0 = 0; k0 < K; k0 += 32) {
    {
      const float* ap = &A[(size_t)(row0 + sar) * K + k0 + sak];
      float4 a0 = *reinterpret_cast<const float4*>(ap);
      float4 a1 = *reinterpret_cast<const float4*>(ap + 4);
      float av[8] = {a0.x, a0.y, a0.z, a0.w, a1.x, a1.y, a1.z, a1.w};
      short8v vh, vl;
#pragma unroll
      for (int j = 0; j < 8; ++j) {
        ushort_t h, l; split_bf16(av[j], h, l);
        vh[j] = (short)h; vl[j] = (short)l;
      }
      *reinterpret_cast<short8v*>(&Ah[sar][sak]) = vh;
      *reinterpret_cast<short8v*>(&Al[sar][sak]) = vl;
    }
    {
      float bv[8];
#pragma unroll
      for (int j = 0; j < 8; ++j)
        bv[j] = B[(size_t)(k0 + sbk + j) * N + col0 + sbc];
      short8v vh, vl;
#pragma unroll
      for (int j = 0; j < 8; ++j) {
        ushort_t h, l; split_bf16(bv[j], h, l);
        vh[j] = (short)h; vl[j] = (short)l;
      }
      *reinterpret_cast<short8v*>(&Bh[sbc][sbk]) = vh;
      *reinterpret_cast<short8v*>(&Bl[sbc][sbk]) = vl;
    }
    __syncthreads();

    short8v ah[4], al[4], bh[2], bl[2];
#pragma unroll
    for (int i = 0; i < 4; ++i) {
      const int r = wm * 64 + i * 16 + l15;
      ah[i] = *reinterpret_cast<const short8v*>(&Ah[r][l16 * 8]);
      al[i] = *reinterpret_cast<const short8v*>(&Al[r][l16 * 8]);
    }
#pragma unroll
    for (int n = 0; n < 2; ++n) {
      const int c = wn * 32 + n * 16 + l15;
      bh[n] = *reinterpret_cast<const short8v*>(&Bh[c][l16 * 8]);
      bl[n] = *reinterpret_cast<const short8v*>(&Bl[c][l16 * 8]);
    }
#pragma unroll
    for (int i = 0; i < 4; ++i)
#pragma unroll
      for (int n = 0; n < 2; ++n) {
        acc[i][n] = __builtin_amdgcn_mfma_f32_16x16x32_bf16(ah[i], bh[n], acc[i][n], 0, 0, 0);
        acc[i][n] = __builtin_amdgcn_mfma_f32_16x16x32_bf16(ah[i], bl[n], acc[i][n], 0, 0, 0);
        acc[i][n] = __builtin_amdgcn_mfma_f32_16x16x32_bf16(al[i], bh[n], acc[i][n], 0, 0, 0);
      }
    __syncthreads();
  }

#pragma unroll
  for (int i = 0; i < 4; ++i) {
#pragma unroll
    for (int n = 0; n < 2; ++n) {
      const int col = col0 + wn * 32 + n * 16 + l15;
      float bs = BIAS ? bias[col] : 0.f;
#pragma unroll
      for (int r = 0; r < 4; ++r) {
        const int row = row0 + wm * 64 + i * 16 + l16 * 4 + r;
        float v = acc[i][n][r] + bs;
        if (RESID) v += resid[(size_t)row * N + col];
        if (RELU)  v = fmaxf(v, 0.f);
        C[(size_t)row * N + col] = v;
      }
    }
  }
}

// ---------------- layernorm over HID=512 ----------------
__global__ __launch_bounds__(64) void layernorm_k(
    const float* __restrict__ in, const float* __restrict__ g,
    const float* __restrict__ b, float* __restrict__ out)
{
  const int row = blockIdx.x, lane = threadIdx.x;
  const float* p = in + (size_t)row * HID + lane * 8;
  float4 v0 = *reinterpret_cast<const float4*>(p);
  float4 v1 = *reinterpret_cast<const float4*>(p + 4);
  float s = v0.x + v0.y + v0.z + v0.w + v1.x + v1.y + v1.z + v1.w;
  s = rsum64(s);
  const float mean = s * (1.0f / HID);
  float x[8] = {v0.x, v0.y, v0.z, v0.w, v1.x, v1.y, v1.z, v1.w};
  float sq = 0.f;
#pragma unroll
  for (int j = 0; j < 8; ++j) { float d = x[j] - mean; sq += d * d; }
  sq = rsum64(sq);
  const float rstd = rsqrtf(sq * (1.0f / HID) + 1e-5f);
  float4 g0 = *reinterpret_cast<const float4*>(&g[lane * 8]);
  float4 g1 = *reinterpret_cast<const float4*>(&g[lane * 8 + 4]);
  float4 b0 = *reinterpret_cast<const float4*>(&b[lane * 8]);
  float4 b1 = *reinterpret_cast<const float4*>(&b[lane * 8 + 4]);
  float gg[8] = {g0.x, g0.y, g0.z, g0.w, g1.x, g1.y, g1.z, g1.w};
  float bb[8] = {b0.x, b0.y, b0.z, b0.w, b1.x, b1.y, b1.z, b1.w};
  float o[8];
#pragma unroll
  for (int j = 0; j < 8; ++j) o[j] = (x[j] - mean) * rstd * gg[j] + bb[j];
  float4 o0 = make_float4(o[0], o[1], o[2], o[3]);
  float4 o1 = make_float4(o[4], o[5], o[6], o[7]);
  float* q = out + (size_t)row * HID + lane * 8;
  *reinterpret_cast<float4*>(q) = o0;
  *reinterpret_cast<float4*>(q + 4) = o1;
}

// ---------------- fast-weight recurrence: 4 waves per (b,h) chain ----------------
// srec4 structure (1 barrier/step) with all uniform-LDS broadcast matvecs
// replaced by per-lane b32 read + v_readlane SGPR broadcast. Moves ~144
// ds_read_b128/step off the (shared, serializing) LDS pipe onto each wave's
// own SIMD VALU pipe. wave0: Wy+y store; wave1: Wq+q softmax; wave2: Wk+k
// softmax; wave3: x prefetch + input softmax + beta/wb.
__global__ __launch_bounds__(256) void srec4r(
    const float* __restrict__ h,
    const float* __restrict__ Wy0, const float* __restrict__ Wq0,
    const float* __restrict__ Wk0, const float* __restrict__ wb0,
    float* __restrict__ ys)
{
  const int bh = blockIdx.x;
  const int bb = bh >> 3, hh = bh & 7;
  const int tid = threadIdx.x;
  const int wv = tid >> 6, lane = tid & 63;

  __shared__ float xs[2][64];
  __shared__ float q_s[2][64];
  __shared__ float k_s[2][64];
  __shared__ float4 betas4[2];

  float W[64];
  float wbr[4] = {0.f, 0.f, 0.f, 0.f};
  float xrA = 0.f, xrB = 0.f;   // raw-x prefetch registers (alternating)
  float xnreg = 0.f;            // softmax(x(t+1)), carried phase A -> phase B

  const float* xp = h + (size_t)bb * HID + hh * 64 + lane;
  float* yp = ys + (size_t)bb * HID + hh * 64 + lane;

  if (wv < 3) {
    const float* base = (wv == 0 ? Wy0 : (wv == 1 ? Wq0 : Wk0)) + (size_t)(hh * 64 + lane) * 64;
#pragma unroll
    for (int j = 0; j < 16; ++j) {
      float4 a = reinterpret_cast<const float4*>(base)[j];
      W[4*j] = a.x; W[4*j+1] = a.y; W[4*j+2] = a.z; W[4*j+3] = a.w;
    }
  } else {
    float4 w = *reinterpret_cast<const float4*>(&wb0[(size_t)(hh * 64 + lane) * 4]);
    wbr[0] = w.x; wbr[1] = w.y; wbr[2] = w.z; wbr[3] = w.w;
    float xr0 = xp[0];
    xrA = xp[(size_t)BSZ * HID];       // raw x(1)
    // softmax(x(0)) -> xs[0]
    float m = rmax64(xr0);
    float e = __expf(xr0 - m);
    float sm = rsum64(e);
    float x0 = e * __builtin_amdgcn_rcpf(sm);
    xs[0][lane] = x0;
    // betas for step 0
    float s0 = rsum64(wbr[0] * x0);
    float s1 = rsum64(wbr[1] * x0);
    float s2 = rsum64(wbr[2] * x0);
    float s3 = rsum64(wbr[3] * x0);
    if (lane == 0)
      betas4[0] = make_float4(1.f / (1.f + __expf(-s0)), 1.f / (1.f + __expf(-s1)),
                              1.f / (1.f + __expf(-s2)), 1.f / (1.f + __expf(-s3)));
  }
  SYNC_LDS();

  auto stepf = [&](int P, float& XCUR, float& XNEXT, int T) {
    // ---------- phase A ----------
    if (wv == 3) {
      if (T + 2 < SLEN) XNEXT = xp[(size_t)(T + 2) * BSZ * HID];  // issue; used next step
      // softmax of raw x(T+1) -> xs[1-P]
      float m = rmax64(XCUR);
      float e = __expf(XCUR - m);
      float sm = rsum64(e);
      float xn_ = e * __builtin_amdgcn_rcpf(sm);
      xs[1 - P][lane] = xn_;
      xnreg = xn_;
    } else {
      float xl = xs[P][lane];            // per-lane b32; lane j holds x_j
      float a0 = 0.f, a1 = 0.f, a2 = 0.f, a3 = 0.f;
#pragma unroll
      for (int j = 0; j < 16; ++j) {     // matvec via readlane broadcast (VALU pipe)
        a0 = fmaf(W[4*j+0], rlf(xl, 4*j+0), a0);
        a1 = fmaf(W[4*j+1], rlf(xl, 4*j+1), a1);
        a2 = fmaf(W[4*j+2], rlf(xl, 4*j+2), a2);
        a3 = fmaf(W[4*j+3], rlf(xl, 4*j+3), a3);
      }
      float acc = (a0 + a1) + (a2 + a3);
      if (wv == 0) {
        yp[(size_t)T * BSZ * HID] = acc;   // fire-and-forget store
      } else {
        float m = rmax64(acc);
        float e = __expf(acc - m);
        float sm = rsum64(e);
        float v = e * __builtin_amdgcn_rcpf(sm);
        float* dst = (wv == 1) ? q_s[P] : k_s[P];
        dst[lane] = v;
      }
    }

    SYNC_LDS();

    // ---------- phase B ----------
    float4 bb4 = betas4[P];
    if (wv < 3) {
      float ql = q_s[P][lane], kl = k_s[P][lane];   // per-lane b32 each
      float dl = ql - kl;                            // lane j holds d_j
      float a0 = 0.f, a1 = 0.f, a2 = 0.f, a3 = 0.f;
#pragma unroll
      for (int j = 0; j < 16; ++j) {     // dX = W d via readlane broadcast
        a0 = fmaf(W[4*j+0], rlf(dl, 4*j+0), a0);
        a1 = fmaf(W[4*j+1], rlf(dl, 4*j+1), a1);
        a2 = fmaf(W[4*j+2], rlf(dl, 4*j+2), a2);
        a3 = fmaf(W[4*j+3], rlf(dl, 4*j+3), a3);
      }
      float dd = (a0 + a1) + (a2 + a3);
      float beta = (wv == 0) ? bb4.x : (wv == 1 ? bb4.y : bb4.z);
      float c = beta * dd;
#pragma unroll
      for (int j = 0; j < 64; ++j)       // W += c * k^T via readlane broadcast
        W[j] = fmaf(c, rlf(kl, j), W[j]);
    } else {
      // wb update (step T), then betas for step T+1 from updated wbr and xnreg
      float ql = q_s[P][lane], kl = k_s[P][lane];
      float dl = ql - kl;
      float d0 = rsum64(wbr[0] * dl);
      float d1 = rsum64(wbr[1] * dl);
      float d2 = rsum64(wbr[2] * dl);
      float d3 = rsum64(wbr[3] * dl);
      float bk = bb4.w * kl;
      wbr[0] = fmaf(bk, d0, wbr[0]);
      wbr[1] = fmaf(bk, d1, wbr[1]);
      wbr[2] = fmaf(bk, d2, wbr[2]);
      wbr[3] = fmaf(bk, d3, wbr[3]);
      float s0 = rsum64(wbr[0] * xnreg);
      float s1 = rsum64(wbr[1] * xnreg);
      float s2 = rsum64(wbr[2] * xnreg);
      float s3 = rsum64(wbr[3] * xnreg);
      if (lane == 0)
        betas4[1 - P] = make_float4(1.f / (1.f + __expf(-s0)), 1.f / (1.f + __expf(-s1)),
                                    1.f / (1.f + __expf(-s2)), 1.f / (1.f + __expf(-s3)));
    }
  };

  for (int t = 0; t < SLEN; t += 2) {
    stepf(0, xrA, xrB, t);
    stepf(1, xrB, xrA, t + 1);
  }
}

extern "C" void kernel_launch(void* const* d_in, const int* in_sizes, int n_in,
                              void* d_out, int out_size, void* d_ws, size_t ws_size,
                              hipStream_t stream)
{
  const float* x     = (const float*)d_in[0];
  const float* in_w  = (const float*)d_in[1];
  const float* in_b  = (const float*)d_in[2];
  const float* Wy    = (const float*)d_in[3];
  const float* Wq    = (const float*)d_in[4];
  const float* Wk    = (const float*)d_in[5];
  const float* wb    = (const float*)d_in[6];
  const float* Wout  = (const float*)d_in[7];
  const float* ln_g  = (const float*)d_in[8];
  const float* ln_b  = (const float*)d_in[9];
  const float* ff_w1 = (const float*)d_in[10];
  const float* ff_b1 = (const float*)d_in[11];
  const float* ff_w2 = (const float*)d_in[12];
  const float* ff_b2 = (const float*)d_in[13];
  float* out = (float*)d_out;

  char* ws = (char*)d_ws;
  float* ys   = (float*)ws;                 // 8MB
  float* ffb  = (float*)(ws + (8u << 20));  // 32MB
  float* ybuf = (float*)(ws + (40u << 20)); // 8MB

  gemm_mfma<HID, 512, true, false, false><<<dim3(HID/128, MROWS/128), 512, 0, stream>>>(
      x, in_w, in_b, nullptr, out);

  for (int l = 0; l < 2; ++l) {
    srec4r<<<128, 256, 0, stream>>>(out,
                                    Wy + (size_t)l * NH * HD * HD,
                                    Wq + (size_t)l * NH * HD * HD,
                                    Wk + (size_t)l * NH * HD * HD,
                                    wb + (size_t)l * NH * HD * 4,
                                    ys);
    gemm_mfma<HID, HID, false, true, false><<<dim3(HID/128, MROWS/128), 512, 0, stream>>>(
        ys, Wout + (size_t)l * HID * HID, nullptr, out, out);
    layernorm_k<<<MROWS, 64, 0, stream>>>(out, ln_g + (size_t)l * HID, ln_b + (size_t)l * HID, ybuf);
    gemm_mfma<FFD, HID, true, false, true><<<dim3(FFD/128, MROWS/128), 512, 0, stream>>>(
        ybuf, ff_w1 + (size_t)l * HID * FFD, ff_b1 + (size_t)l * FFD, nullptr, ffb);
    gemm_mfma<HID, FFD, true, true, false><<<dim3(HID/128, MROWS/128), 512, 0, stream>>>(
        ffb, ff_w2 + (size_t)l * FFD * HID, ff_b2 + (size_t)l * HID, out, out);
  }
}

// Round 5
// 943.920 us; speedup vs baseline: 1.8767x; 1.0736x over previous
//
#include <hip/hip_runtime.h>
#include <hip/hip_bf16.h>
#include <math.h>

#define SLEN 256
#define BSZ  16
#define NH   8
#define HD   64
#define HID  512
#define FFD  2048
#define MROWS (SLEN*BSZ)   // 4096

typedef __attribute__((ext_vector_type(8))) short short8v;
typedef __attribute__((ext_vector_type(4))) float float4v;
typedef unsigned short ushort_t;

// lgkmcnt-only barrier: LDS visibility without draining vmcnt (keeps global
// prefetch loads in flight across the barrier; __syncthreads would drain them).
#define SYNC_LDS() do { \
  asm volatile("s_waitcnt lgkmcnt(0)" ::: "memory"); \
  __builtin_amdgcn_s_barrier(); \
} while (0)

// ---- all-VALU wave-64 reductions: 4 DPP xor levels + row_bcast15/31 + readlane ----
template<int C> __device__ __forceinline__ float dppf(float x){
  return __int_as_float(__builtin_amdgcn_update_dpp(__float_as_int(x), __float_as_int(x), C, 0xF, 0xF, false));
}

__device__ __forceinline__ float rsum64(float v){
  v += dppf<0xB1>(v);   // xor 1
  v += dppf<0x4E>(v);   // xor 2
  v += dppf<0x141>(v);  // row_half_mirror (xor 4 level)
  v += dppf<0x140>(v);  // row_mirror      (xor 8 level)
  v += __int_as_float(__builtin_amdgcn_update_dpp(0, __float_as_int(v), 0x142, 0xa, 0xF, false)); // bcast15
  v += __int_as_float(__builtin_amdgcn_update_dpp(0, __float_as_int(v), 0x143, 0xc, 0xF, false)); // bcast31
  return __int_as_float(__builtin_amdgcn_readlane(__float_as_int(v), 63));
}

__device__ __forceinline__ void split_bf16(float f, ushort_t& h, ushort_t& l){
  unsigned u = __float_as_uint(f);
  unsigned r = u + (0x7fffu + ((u >> 16) & 1u));
  h = (ushort_t)(r >> 16);
  float hf = __uint_as_float(((unsigned)h) << 16);
  float lo = f - hf;
  unsigned u2 = __float_as_uint(lo);
  unsigned r2 = u2 + (0x7fffu + ((u2 >> 16) & 1u));
  l = (ushort_t)(r2 >> 16);
}

// ---------------- MFMA GEMM, bf16x3 split (~fp32 accuracy) ----------------
template<int N, int K, bool BIAS, bool RESID, bool RELU>
__global__ __launch_bounds__(512) void gemm_mfma(
    const float* __restrict__ A, const float* __restrict__ B,
    const float* __restrict__ bias, const float* __restrict__ resid,
    float* __restrict__ C)
{
  __shared__ ushort_t Ah[128][40];
  __shared__ ushort_t Al[128][40];
  __shared__ ushort_t Bh[128][40];   // [col][k] (transposed)
  __shared__ ushort_t Bl[128][40];

  const int tid = threadIdx.x;
  const int wv = tid >> 6, lane = tid & 63;
  const int wm = wv >> 2, wn = wv & 3;
  const int l15 = lane & 15, l16 = lane >> 4;
  const int row0 = blockIdx.y * 128, col0 = blockIdx.x * 128;

  const int sar = tid >> 2, sak = (tid & 3) * 8;
  const int sbc = tid & 127, sbk = (tid >> 7) * 8;

  float4v acc[4][2];
#pragma unroll
  for (int i = 0; i < 4; ++i)
#pragma unroll
    for (int n = 0; n < 2; ++n) acc[i][n] = (float4v)(0.f);

  for (int k0 = 0; k0 < K; k0 += 32) {
    {
      const float* ap = &A[(size_t)(row0 + sar) * K + k0 + sak];
      float4 a0 = *reinterpret_cast<const float4*>(ap);
      float4 a1 = *reinterpret_cast<const float4*>(ap + 4);
      float av[8] = {a0.x, a0.y, a0.z, a0.w, a1.x, a1.y, a1.z, a1.w};
      short8v vh, vl;
#pragma unroll
      for (int j = 0; j < 8; ++j) {
        ushort_t h, l; split_bf16(av[j], h, l);
        vh[j] = (short)h; vl[j] = (short)l;
      }
      *reinterpret_cast<short8v*>(&Ah[sar][sak]) = vh;
      *reinterpret_cast<short8v*>(&Al[sar][sak]) = vl;
    }
    {
      float bv[8];
#pragma unroll
      for (int j = 0; j < 8; ++j)
        bv[j] = B[(size_t)(k0 + sbk + j) * N + col0 + sbc];
      short8v vh, vl;
#pragma unroll
      for (int j = 0; j < 8; ++j) {
        ushort_t h, l; split_bf16(bv[j], h, l);
        vh[j] = (short)h; vl[j] = (short)l;
      }
      *reinterpret_cast<short8v*>(&Bh[sbc][sbk]) = vh;
      *reinterpret_cast<short8v*>(&Bl[sbc][sbk]) = vl;
    }
    __syncthreads();

    short8v ah[4], al[4], bh[2], bl[2];
#pragma unroll
    for (int i = 0; i < 4; ++i) {
      const int r = wm * 64 + i * 16 + l15;
      ah[i] = *reinterpret_cast<const short8v*>(&Ah[r][l16 * 8]);
      al[i] = *reinterpret_cast<const short8v*>(&Al[r][l16 * 8]);
    }
#pragma unroll
    for (int n = 0; n < 2; ++n) {
      const int c = wn * 32 + n * 16 + l15;
      bh[n] = *reinterpret_cast<const short8v*>(&Bh[c][l16 * 8]);
      bl[n] = *reinterpret_cast<const short8v*>(&Bl[c][l16 * 8]);
    }
#pragma unroll
    for (int i = 0; i < 4; ++i)
#pragma unroll
      for (int n = 0; n < 2; ++n) {
        acc[i][n] = __builtin_amdgcn_mfma_f32_16x16x32_bf16(ah[i], bh[n], acc[i][n], 0, 0, 0);
        acc[i][n] = __builtin_amdgcn_mfma_f32_16x16x32_bf16(ah[i], bl[n], acc[i][n], 0, 0, 0);
        acc[i][n] = __builtin_amdgcn_mfma_f32_16x16x32_bf16(al[i], bh[n], acc[i][n], 0, 0, 0);
      }
    __syncthreads();
  }

#pragma unroll
  for (int i = 0; i < 4; ++i) {
#pragma unroll
    for (int n = 0; n < 2; ++n) {
      const int col = col0 + wn * 32 + n * 16 + l15;
      float bs = BIAS ? bias[col] : 0.f;
#pragma unroll
      for (int r = 0; r < 4; ++r) {
        const int row = row0 + wm * 64 + i * 16 + l16 * 4 + r;
        float v = acc[i][n][r] + bs;
        if (RESID) v += resid[(size_t)row * N + col];
        if (RELU)  v = fmaxf(v, 0.f);
        C[(size_t)row * N + col] = v;
      }
    }
  }
}

// ---------------- layernorm over HID=512 ----------------
__global__ __launch_bounds__(64) void layernorm_k(
    const float* __restrict__ in, const float* __restrict__ g,
    const float* __restrict__ b, float* __restrict__ out)
{
  const int row = blockIdx.x, lane = threadIdx.x;
  const float* p = in + (size_t)row * HID + lane * 8;
  float4 v0 = *reinterpret_cast<const float4*>(p);
  float4 v1 = *reinterpret_cast<const float4*>(p + 4);
  float s = v0.x + v0.y + v0.z + v0.w + v1.x + v1.y + v1.z + v1.w;
  s = rsum64(s);
  const float mean = s * (1.0f / HID);
  float x[8] = {v0.x, v0.y, v0.z, v0.w, v1.x, v1.y, v1.z, v1.w};
  float sq = 0.f;
#pragma unroll
  for (int j = 0; j < 8; ++j) { float d = x[j] - mean; sq += d * d; }
  sq = rsum64(sq);
  const float rstd = rsqrtf(sq * (1.0f / HID) + 1e-5f);
  float4 g0 = *reinterpret_cast<const float4*>(&g[lane * 8]);
  float4 g1 = *reinterpret_cast<const float4*>(&g[lane * 8 + 4]);
  float4 b0 = *reinterpret_cast<const float4*>(&b[lane * 8]);
  float4 b1 = *reinterpret_cast<const float4*>(&b[lane * 8 + 4]);
  float gg[8] = {g0.x, g0.y, g0.z, g0.w, g1.x, g1.y, g1.z, g1.w};
  float bb[8] = {b0.x, b0.y, b0.z, b0.w, b1.x, b1.y, b1.z, b1.w};
  float o[8];
#pragma unroll
  for (int j = 0; j < 8; ++j) o[j] = (x[j] - mean) * rstd * gg[j] + bb[j];
  float4 o0 = make_float4(o[0], o[1], o[2], o[3]);
  float4 o1 = make_float4(o[4], o[5], o[6], o[7]);
  float* q = out + (size_t)row * HID + lane * 8;
  *reinterpret_cast<float4*>(q) = o0;
  *reinterpret_cast<float4*>(q + 4) = o1;
}

// ---------------- fast-weight recurrence: 4 waves per (b,h) chain ----------------
// Proven srec4 structure (1 barrier/step, LDS double-buffer, vmcnt-preserving
// barrier), with the reduction critical path trimmed:
//  - softmaxes computed WITHOUT max-subtraction (shift-invariant, exact math;
//    activations are O(10) so exp cannot overflow) -> one rmax64 removed from
//    every phase-A chain
//  - wave3 phase B: s_i = rsum64(wbr_i.xn) + d_i * rsum64(bk.xn) -> 9 fully
//    independent rsum64s issued together instead of 2 dependent groups
//  - sigmoid via rcp instead of exact divide
//  - 8-accumulator matvecs (half the fma dependency depth)
__global__ __launch_bounds__(256) void srec4t(
    const float* __restrict__ h,
    const float* __restrict__ Wy0, const float* __restrict__ Wq0,
    const float* __restrict__ Wk0, const float* __restrict__ wb0,
    float* __restrict__ ys)
{
  const int bh = blockIdx.x;
  const int bb = bh >> 3, hh = bh & 7;
  const int tid = threadIdx.x;
  const int wv = tid >> 6, lane = tid & 63;

  __shared__ float xs[2][64];
  __shared__ float q_s[2][64];
  __shared__ float k_s[2][64];
  __shared__ float4 betas4[2];

  float W[64];
  float wbr[4] = {0.f, 0.f, 0.f, 0.f};
  float xrA = 0.f, xrB = 0.f;   // raw-x prefetch registers (alternating)
  float xnreg = 0.f;            // softmax(x(t+1)), carried phase A -> phase B

  const float* xp = h + (size_t)bb * HID + hh * 64 + lane;
  float* yp = ys + (size_t)bb * HID + hh * 64 + lane;

  if (wv < 3) {
    const float* base = (wv == 0 ? Wy0 : (wv == 1 ? Wq0 : Wk0)) + (size_t)(hh * 64 + lane) * 64;
#pragma unroll
    for (int j = 0; j < 16; ++j) {
      float4 a = reinterpret_cast<const float4*>(base)[j];
      W[4*j] = a.x; W[4*j+1] = a.y; W[4*j+2] = a.z; W[4*j+3] = a.w;
    }
  } else {
    float4 w = *reinterpret_cast<const float4*>(&wb0[(size_t)(hh * 64 + lane) * 4]);
    wbr[0] = w.x; wbr[1] = w.y; wbr[2] = w.z; wbr[3] = w.w;
    float xr0 = xp[0];
    xrA = xp[(size_t)BSZ * HID];       // raw x(1)
    // softmax(x(0)) -> xs[0]   (no max-sub: shift-invariant)
    float e = __expf(xr0);
    float sm = rsum64(e);
    float x0 = e * __builtin_amdgcn_rcpf(sm);
    xs[0][lane] = x0;
    // betas for step 0
    float s0 = rsum64(wbr[0] * x0);
    float s1 = rsum64(wbr[1] * x0);
    float s2 = rsum64(wbr[2] * x0);
    float s3 = rsum64(wbr[3] * x0);
    if (lane == 0)
      betas4[0] = make_float4(__builtin_amdgcn_rcpf(1.f + __expf(-s0)),
                              __builtin_amdgcn_rcpf(1.f + __expf(-s1)),
                              __builtin_amdgcn_rcpf(1.f + __expf(-s2)),
                              __builtin_amdgcn_rcpf(1.f + __expf(-s3)));
  }
  SYNC_LDS();

  auto stepf = [&](int P, float& XCUR, float& XNEXT, int T) {
    // ---------- phase A ----------
    if (wv == 3) {
      if (T + 2 < SLEN) XNEXT = xp[(size_t)(T + 2) * BSZ * HID];  // issue; used next step
      // softmax of raw x(T+1) -> xs[1-P]   (no max-sub)
      float e = __expf(XCUR);
      float sm = rsum64(e);
      float xn_ = e * __builtin_amdgcn_rcpf(sm);
      xs[1 - P][lane] = xn_;
      xnreg = xn_;
    } else {
      const float4* xv = reinterpret_cast<const float4*>(xs[P]);
      float a0=0.f,a1=0.f,a2=0.f,a3=0.f,a4=0.f,a5=0.f,a6=0.f,a7=0.f;
#pragma unroll
      for (int j = 0; j < 8; ++j) {
        float4 x1 = xv[2*j], x2 = xv[2*j+1];
        a0 = fmaf(W[8*j+0], x1.x, a0);
        a1 = fmaf(W[8*j+1], x1.y, a1);
        a2 = fmaf(W[8*j+2], x1.z, a2);
        a3 = fmaf(W[8*j+3], x1.w, a3);
        a4 = fmaf(W[8*j+4], x2.x, a4);
        a5 = fmaf(W[8*j+5], x2.y, a5);
        a6 = fmaf(W[8*j+6], x2.z, a6);
        a7 = fmaf(W[8*j+7], x2.w, a7);
      }
      float acc = ((a0 + a1) + (a2 + a3)) + ((a4 + a5) + (a6 + a7));
      if (wv == 0) {
        yp[(size_t)T * BSZ * HID] = acc;   // fire-and-forget store
      } else {
        float e = __expf(acc);             // no max-sub
        float sm = rsum64(e);
        float v = e * __builtin_amdgcn_rcpf(sm);
        float* dst = (wv == 1) ? q_s[P] : k_s[P];
        dst[lane] = v;
      }
    }

    SYNC_LDS();

    // ---------- phase B ----------
    float4 bb4 = betas4[P];
    if (wv < 3) {
      const float4* qv = reinterpret_cast<const float4*>(q_s[P]);
      const float4* kv = reinterpret_cast<const float4*>(k_s[P]);
      float4 karr[16];
      float a0=0.f,a1=0.f,a2=0.f,a3=0.f,a4=0.f,a5=0.f,a6=0.f,a7=0.f;
#pragma unroll
      for (int j = 0; j < 8; ++j) {
        float4 q1 = qv[2*j], k1 = kv[2*j];
        float4 q2 = qv[2*j+1], k2 = kv[2*j+1];
        karr[2*j] = k1; karr[2*j+1] = k2;
        a0 = fmaf(W[8*j+0], q1.x - k1.x, a0);
        a1 = fmaf(W[8*j+1], q1.y - k1.y, a1);
        a2 = fmaf(W[8*j+2], q1.z - k1.z, a2);
        a3 = fmaf(W[8*j+3], q1.w - k1.w, a3);
        a4 = fmaf(W[8*j+4], q2.x - k2.x, a4);
        a5 = fmaf(W[8*j+5], q2.y - k2.y, a5);
        a6 = fmaf(W[8*j+6], q2.z - k2.z, a6);
        a7 = fmaf(W[8*j+7], q2.w - k2.w, a7);
      }
      float dd = ((a0 + a1) + (a2 + a3)) + ((a4 + a5) + (a6 + a7));
      float beta = (wv == 0) ? bb4.x : (wv == 1 ? bb4.y : bb4.z);
      float c = beta * dd;
#pragma unroll
      for (int j = 0; j < 16; ++j) {
        float4 k4 = karr[j];
        W[4*j]   = fmaf(c, k4.x, W[4*j]);
        W[4*j+1] = fmaf(c, k4.y, W[4*j+1]);
        W[4*j+2] = fmaf(c, k4.z, W[4*j+2]);
        W[4*j+3] = fmaf(c, k4.w, W[4*j+3]);
      }
    } else {
      // wb update + next-step betas, via 9 INDEPENDENT reductions:
      // s_i(next) = (wbr_i + bk*d_i) . xn = rsum(wbr_i*xn) + d_i * rsum(bk*xn)
      float ql = q_s[P][lane], kl = k_s[P][lane];
      float dl = ql - kl;
      float bk = bb4.w * kl;
      float u0 = rsum64(wbr[0] * xnreg);
      float u1 = rsum64(wbr[1] * xnreg);
      float u2 = rsum64(wbr[2] * xnreg);
      float u3 = rsum64(wbr[3] * xnreg);
      float d0 = rsum64(wbr[0] * dl);
      float d1 = rsum64(wbr[1] * dl);
      float d2 = rsum64(wbr[2] * dl);
      float d3 = rsum64(wbr[3] * dl);
      float g  = rsum64(bk * xnreg);
      wbr[0] = fmaf(bk, d0, wbr[0]);
      wbr[1] = fmaf(bk, d1, wbr[1]);
      wbr[2] = fmaf(bk, d2, wbr[2]);
      wbr[3] = fmaf(bk, d3, wbr[3]);
      float s0 = fmaf(d0, g, u0);
      float s1 = fmaf(d1, g, u1);
      float s2 = fmaf(d2, g, u2);
      float s3 = fmaf(d3, g, u3);
      if (lane == 0)
        betas4[1 - P] = make_float4(__builtin_amdgcn_rcpf(1.f + __expf(-s0)),
                                    __builtin_amdgcn_rcpf(1.f + __expf(-s1)),
                                    __builtin_amdgcn_rcpf(1.f + __expf(-s2)),
                                    __builtin_amdgcn_rcpf(1.f + __expf(-s3)));
    }
  };

  for (int t = 0; t < SLEN; t += 2) {
    stepf(0, xrA, xrB, t);
    stepf(1, xrB, xrA, t + 1);
  }
}

extern "C" void kernel_launch(void* const* d_in, const int* in_sizes, int n_in,
                              void* d_out, int out_size, void* d_ws, size_t ws_size,
                              hipStream_t stream)
{
  const float* x     = (const float*)d_in[0];
  const float* in_w  = (const float*)d_in[1];
  const float* in_b  = (const float*)d_in[2];
  const float* Wy    = (const float*)d_in[3];
  const float* Wq    = (const float*)d_in[4];
  const float* Wk    = (const float*)d_in[5];
  const float* wb    = (const float*)d_in[6];
  const float* Wout  = (const float*)d_in[7];
  const float* ln_g  = (const float*)d_in[8];
  const float* ln_b  = (const float*)d_in[9];
  const float* ff_w1 = (const float*)d_in[10];
  const float* ff_b1 = (const float*)d_in[11];
  const float* ff_w2 = (const float*)d_in[12];
  const float* ff_b2 = (const float*)d_in[13];
  float* out = (float*)d_out;

  char* ws = (char*)d_ws;
  float* ys   = (float*)ws;                 // 8MB
  float* ffb  = (float*)(ws + (8u << 20));  // 32MB
  float* ybuf = (float*)(ws + (40u << 20)); // 8MB

  gemm_mfma<HID, 512, true, false, false><<<dim3(HID/128, MROWS/128), 512, 0, stream>>>(
      x, in_w, in_b, nullptr, out);

  for (int l = 0; l < 2; ++l) {
    srec4t<<<128, 256, 0, stream>>>(out,
                                    Wy + (size_t)l * NH * HD * HD,
                                    Wq + (size_t)l * NH * HD * HD,
                                    Wk + (size_t)l * NH * HD * HD,
                                    wb + (size_t)l * NH * HD * 4,
                                    ys);
    gemm_mfma<HID, HID, false, true, false><<<dim3(HID/128, MROWS/128), 512, 0, stream>>>(
        ys, Wout + (size_t)l * HID * HID, nullptr, out, out);
    layernorm_k<<<MROWS, 64, 0, stream>>>(out, ln_g + (size_t)l * HID, ln_b + (size_t)l * HID, ybuf);
    gemm_mfma<FFD, HID, true, false, true><<<dim3(FFD/128, MROWS/128), 512, 0, stream>>>(
        ybuf, ff_w1 + (size_t)l * HID * FFD, ff_b1 + (size_t)l * FFD, nullptr, ffb);
    gemm_mfma<HID, FFD, true, true, false><<<dim3(HID/128, MROWS/128), 512, 0, stream>>>(
        ffb, ff_w2 + (size_t)l * FFD * HID, ff_b2 + (size_t)l * HID, out, out);
  }
}